// Round 1
// baseline (338.399 us; speedup 1.0000x reference)
//
#include <hip/hip_runtime.h>

#define NN 2048
#define BB 8
#define LL 64
#define ADA 16
#define DH 16
#define HH 4
#define HB 32
#define NSLICE 4

// ---------------- K1: A = rowsoftmax(relu(E E^T)) ----------------
__global__ __launch_bounds__(256) void k_rowsoftmax(const float* __restrict__ E,
                                                    float* __restrict__ A) {
  __shared__ float row[NN];
  __shared__ float red[256];
  const int n = blockIdx.x;
  const int t = threadIdx.x;
  float e[ADA];
  const float* En = E + (size_t)n * ADA;
#pragma unroll
  for (int d = 0; d < ADA; ++d) e[d] = En[d];
  float lsum = 0.f;
  for (int m = t; m < NN; m += 256) {
    const float* Em = E + (size_t)m * ADA;
    float s = 0.f;
#pragma unroll
    for (int d = 0; d < ADA; ++d) s = fmaf(e[d], Em[d], s);
    s = fmaxf(s, 0.f);
    float p = __expf(s - 20.f);  // fixed shift; scores bounded (~<47), cancels in normalize
    row[m] = p;
    lsum += p;
  }
  red[t] = lsum;
  __syncthreads();
  for (int off = 128; off > 0; off >>= 1) {
    if (t < off) red[t] += red[t + off];
    __syncthreads();
  }
  const float inv = 1.f / red[0];
  for (int m = t; m < NN; m += 256) A[(size_t)n * NN + m] = row[m] * inv;
}

// ---------------- K2: cg[b] = A @ c[b]  (M=2048,K=2048,N=64 per batch) ----------------
__global__ __launch_bounds__(256) void k_gemm_Ac(const float* __restrict__ A,
                                                 const float* __restrict__ c,
                                                 float* __restrict__ cg) {
  __shared__ float At[64][68];  // [kk][row], padded for bank-conflict-free f4 reads
  __shared__ float cs[64][64];  // [kk][col]
  const int t = threadIdx.x;
  const int n0 = blockIdx.x * 64;
  const int b = blockIdx.y;
  const int tx = t & 15;  // col quad
  const int ty = t >> 4;  // row quad
  const float* cb = c + (size_t)b * NN * LL;
  float acc[4][4];
#pragma unroll
  for (int i = 0; i < 4; ++i)
#pragma unroll
    for (int j = 0; j < 4; ++j) acc[i][j] = 0.f;

  for (int k0 = 0; k0 < NN; k0 += 64) {
    __syncthreads();
#pragma unroll
    for (int rep = 0; rep < 4; ++rep) {
      int idx = t + rep * 256;
      int q = idx & 15;
      int r = idx >> 4;  // 0..63 (row for A, kk for c)
      float4 av = *(const float4*)(A + (size_t)(n0 + r) * NN + k0 + 4 * q);
      At[4 * q + 0][r] = av.x;
      At[4 * q + 1][r] = av.y;
      At[4 * q + 2][r] = av.z;
      At[4 * q + 3][r] = av.w;
      float4 cv = *(const float4*)(cb + (size_t)(k0 + r) * LL + 4 * q);
      *(float4*)&cs[r][4 * q] = cv;
    }
    __syncthreads();
#pragma unroll 8
    for (int kk = 0; kk < 64; ++kk) {
      float4 av = *(const float4*)&At[kk][4 * ty];
      float4 cv = *(const float4*)&cs[kk][4 * tx];
      float a[4] = {av.x, av.y, av.z, av.w};
      float cc[4] = {cv.x, cv.y, cv.z, cv.w};
#pragma unroll
      for (int i = 0; i < 4; ++i)
#pragma unroll
        for (int j = 0; j < 4; ++j) acc[i][j] = fmaf(a[i], cc[j], acc[i][j]);
    }
  }
  float* outp = cg + ((size_t)b * NN + n0) * LL;
#pragma unroll
  for (int i = 0; i < 4; ++i) {
    float4 v = make_float4(acc[i][0], acc[i][1], acc[i][2], acc[i][3]);
    *(float4*)(outp + (size_t)(4 * ty + i) * LL + 4 * tx) = v;
  }
}

// ---------------- K3: ct = tanh(AGCRN combine) ----------------
// ct[b,n,o] = tanh( sum_{k,i} x_k[b,n,i] * (sum_d E[n,d] Wp[d,k,i,o]) + sum_d E[n,d] bp[d,o] )
__global__ __launch_bounds__(256) void k_gcn(const float* __restrict__ E,
                                             const float* __restrict__ Wp,
                                             const float* __restrict__ bp,
                                             const float* __restrict__ c,
                                             const float* __restrict__ cg,
                                             float* __restrict__ ct) {
  __shared__ float xs[4][2][BB][LL];  // [node][k][b][i]
  __shared__ float Es[4][ADA];
  const int t = threadIdx.x;
  const int n0 = blockIdx.x * 4;
  const int o = t & 63;
  const int g = t >> 6;  // 0..3 -> batches g and g+4
  if (t < 4 * ADA) Es[t >> 4][t & 15] = E[(size_t)(n0 + (t >> 4)) * ADA + (t & 15)];
#pragma unroll
  for (int rep = 0; rep < 2; ++rep) {
    int idx = t + rep * 256;  // 0..511
    int q = idx & 15;
    int bb = (idx >> 4) & 7;
    int nl = idx >> 7;
    const size_t base = ((size_t)bb * NN + n0 + nl) * LL + 4 * q;
    *(float4*)&xs[nl][0][bb][4 * q] = *(const float4*)(c + base);
    *(float4*)&xs[nl][1][bb][4 * q] = *(const float4*)(cg + base);
  }
  __syncthreads();

  float acc[4][2];
#pragma unroll
  for (int nl = 0; nl < 4; ++nl) {
    float bnv = 0.f;
#pragma unroll
    for (int d = 0; d < ADA; ++d) bnv = fmaf(Es[nl][d], bp[d * LL + o], bnv);
    acc[nl][0] = bnv;
    acc[nl][1] = bnv;
  }
  for (int k = 0; k < 2; ++k) {
    for (int i = 0; i < LL; ++i) {
      float wd[ADA];
#pragma unroll
      for (int d = 0; d < ADA; ++d) wd[d] = Wp[(((size_t)d * 2 + k) * LL + i) * LL + o];
#pragma unroll
      for (int nl = 0; nl < 4; ++nl) {
        float w = 0.f;
#pragma unroll
        for (int d = 0; d < ADA; ++d) w = fmaf(Es[nl][d], wd[d], w);
        acc[nl][0] = fmaf(xs[nl][k][g][i], w, acc[nl][0]);
        acc[nl][1] = fmaf(xs[nl][k][g + 4][i], w, acc[nl][1]);
      }
    }
  }
#pragma unroll
  for (int nl = 0; nl < 4; ++nl) {
    ct[((size_t)g * NN + n0 + nl) * LL + o] = tanhf(acc[nl][0]);
    ct[((size_t)(g + 4) * NN + n0 + nl) * LL + o] = tanhf(acc[nl][1]);
  }
}

// ---------------- K4: fused attention partials ----------------
// theta[h*B+b,n,d] = state[b,n,16h+d]; scores = theta theta^T / 4; fixed-shift softmax sums.
__global__ __launch_bounds__(256) void k_attn(const float* __restrict__ state,
                                              const float* __restrict__ ctv,
                                              float* __restrict__ part) {
  __shared__ float Ks[128][16];
  __shared__ float Vs[128][16];
  const int hb = blockIdx.x;
  const int h = hb >> 3;  // hb / B
  const int b = hb & 7;   // hb % B
  const int q0 = blockIdx.y * 256;
  const int s = blockIdx.z;
  const int t = threadIdx.x;
  const float* sb = state + (size_t)b * NN * LL + h * DH;
  const float* vb = ctv + (size_t)b * NN * LL + h * DH;
  float q[16];
  {
    const float* qp = sb + (size_t)(q0 + t) * LL;
#pragma unroll
    for (int j = 0; j < 4; ++j) {
      float4 v = *(const float4*)(qp + 4 * j);
      q[4 * j + 0] = v.x * 0.25f;
      q[4 * j + 1] = v.y * 0.25f;
      q[4 * j + 2] = v.z * 0.25f;
      q[4 * j + 3] = v.w * 0.25f;
    }
  }
  float num[16];
#pragma unroll
  for (int d = 0; d < 16; ++d) num[d] = 0.f;
  float den = 0.f;
  const int m0 = s * (NN / NSLICE);
  const int r = t >> 1;
  const int half = (t & 1) * 8;
  for (int mt = 0; mt < NN / NSLICE; mt += 128) {
    __syncthreads();
    const float* kp = sb + (size_t)(m0 + mt + r) * LL + half;
    const float* vp = vb + (size_t)(m0 + mt + r) * LL + half;
    float4 k0v = *(const float4*)(kp);
    float4 k1v = *(const float4*)(kp + 4);
    float4 v0v = *(const float4*)(vp);
    float4 v1v = *(const float4*)(vp + 4);
    *(float4*)&Ks[r][half] = k0v;
    *(float4*)&Ks[r][half + 4] = k1v;
    *(float4*)&Vs[r][half] = v0v;
    *(float4*)&Vs[r][half + 4] = v1v;
    __syncthreads();
    for (int m = 0; m < 128; ++m) {
      float sc = 0.f;
#pragma unroll
      for (int d = 0; d < 16; ++d) sc = fmaf(q[d], Ks[m][d], sc);
      float p = __expf(sc - 10.f);  // fixed shift, cancels in num/den
      den += p;
#pragma unroll
      for (int d = 0; d < 16; ++d) num[d] = fmaf(p, Vs[m][d], num[d]);
    }
  }
  float* pp = part + (((size_t)hb * NN + q0 + t) * NSLICE + s) * 17;
#pragma unroll
  for (int d = 0; d < 16; ++d) pp[d] = num[d];
  pp[16] = den;
}

// ---------------- K5: reduce partials, write output ----------------
__global__ __launch_bounds__(256) void k_reduce(const float* __restrict__ part,
                                                float* __restrict__ out) {
  const int idx = blockIdx.x * 256 + threadIdx.x;
  const int hb = idx >> 11;
  const int n = idx & 2047;
  const int h = hb >> 3;
  const int b = hb & 7;
  const float* pp = part + ((size_t)hb * NN + n) * NSLICE * 17;
  float num[16];
#pragma unroll
  for (int d = 0; d < 16; ++d) num[d] = 0.f;
  float den = 0.f;
#pragma unroll
  for (int s2 = 0; s2 < NSLICE; ++s2) {
#pragma unroll
    for (int d = 0; d < 16; ++d) num[d] += pp[s2 * 17 + d];
    den += pp[s2 * 17 + 16];
  }
  const float inv = -1.f / den;
  float* op = out + ((size_t)b * NN + n) * LL + h * DH;
#pragma unroll
  for (int d = 0; d < 16; ++d) op[d] = num[d] * inv;
}

extern "C" void kernel_launch(void* const* d_in, const int* in_sizes, int n_in,
                              void* d_out, int out_size, void* d_ws, size_t ws_size,
                              hipStream_t stream) {
  // inputs (setup_inputs order): 0 c, 1 c_condition, 2 c_disease, 3 state, 4 emb_normal,
  // 5..12 dead query-path weights, 13 Wp_gcn, 14 bp_gcn
  const float* c = (const float*)d_in[0];
  const float* state = (const float*)d_in[3];
  const float* E = (const float*)d_in[4];
  const float* Wp = (const float*)d_in[13];
  const float* bp = (const float*)d_in[14];
  float* out = (float*)d_out;

  float* A = (float*)d_ws;                        // 2048*2048
  float* cg = A + (size_t)NN * NN;                // 8*2048*64
  float* ctb = cg + (size_t)BB * NN * LL;         // 8*2048*64
  float* part = ctb + (size_t)BB * NN * LL;       // 32*2048*4*17

  k_rowsoftmax<<<NN, 256, 0, stream>>>(E, A);
  k_gemm_Ac<<<dim3(NN / 64, BB), 256, 0, stream>>>(A, c, cg);
  k_gcn<<<NN / 4, 256, 0, stream>>>(E, Wp, bp, c, cg, ctb);
  k_attn<<<dim3(HB, NN / 256, NSLICE), 256, 0, stream>>>(state, ctb, part);
  k_reduce<<<(HB * NN) / 256, 256, 0, stream>>>(part, out);
}

// Round 3
// 264.183 us; speedup vs baseline: 1.2809x; 1.2809x over previous
//
#include <hip/hip_runtime.h>
#include <hip/hip_bf16.h>

#define NN 2048
#define BB 8
#define LL 64
#define ADA 16
#define DH 16
#define HB 32

typedef __attribute__((ext_vector_type(4))) short bf16x4;
typedef __attribute__((ext_vector_type(4))) float f32x4;

// __has_builtin(__builtin_amdgcn_mfma_*) is FALSE on the host pass of hipcc's
// dual compile -> must guard with __HIP_DEVICE_COMPILE__ and give the host a
// parse-only dummy (host never codegens device bodies).
#if defined(__HIP_DEVICE_COMPILE__)
#if __has_builtin(__builtin_amdgcn_mfma_f32_16x16x16bf16_1k)
#define MFMA16(a, b, c) __builtin_amdgcn_mfma_f32_16x16x16bf16_1k(a, b, c, 0, 0, 0)
#elif __has_builtin(__builtin_amdgcn_mfma_f32_16x16x16_bf16)
#define MFMA16(a, b, c) __builtin_amdgcn_mfma_f32_16x16x16_bf16(a, b, c, 0, 0, 0)
#else
#error "no 16x16x16 bf16 mfma builtin on device"
#endif
#else
#define MFMA16(a, b, c) (c)
#endif

__device__ inline unsigned short f2bf(float x) {
  __hip_bfloat16 h = __float2bfloat16(x);
  return *reinterpret_cast<unsigned short*>(&h);
}

// ---------------- K1: A = rowsoftmax(relu(E E^T)), 2 rows/block ----------------
__global__ __launch_bounds__(256) void k_rowsoftmax(const float* __restrict__ E,
                                                    float* __restrict__ A) {
  __shared__ float row[2][NN];
  __shared__ float red[2][256];
  const int n = blockIdx.x * 2;
  const int t = threadIdx.x;
  float4 e0[4], e1[4];
  const float4* E0 = (const float4*)(E + (size_t)n * ADA);
  const float4* E1 = (const float4*)(E + (size_t)(n + 1) * ADA);
#pragma unroll
  for (int j = 0; j < 4; ++j) { e0[j] = E0[j]; e1[j] = E1[j]; }
  float l0 = 0.f, l1 = 0.f;
  for (int m = t; m < NN; m += 256) {
    const float4* Em = (const float4*)(E + (size_t)m * ADA);
    float s0 = 0.f, s1 = 0.f;
#pragma unroll
    for (int j = 0; j < 4; ++j) {
      float4 ev = Em[j];
      s0 = fmaf(e0[j].x, ev.x, fmaf(e0[j].y, ev.y, fmaf(e0[j].z, ev.z, fmaf(e0[j].w, ev.w, s0))));
      s1 = fmaf(e1[j].x, ev.x, fmaf(e1[j].y, ev.y, fmaf(e1[j].z, ev.z, fmaf(e1[j].w, ev.w, s1))));
    }
    float p0 = __expf(fmaxf(s0, 0.f) - 20.f);  // fixed shift; cancels in normalize
    float p1 = __expf(fmaxf(s1, 0.f) - 20.f);
    row[0][m] = p0; row[1][m] = p1;
    l0 += p0; l1 += p1;
  }
  red[0][t] = l0; red[1][t] = l1;
  __syncthreads();
  for (int off = 128; off > 0; off >>= 1) {
    if (t < off) { red[0][t] += red[0][t + off]; red[1][t] += red[1][t + off]; }
    __syncthreads();
  }
  const float i0 = 1.f / red[0][0], i1 = 1.f / red[1][0];
  for (int m = t; m < NN; m += 256) {
    A[(size_t)n * NN + m] = row[0][m] * i0;
    A[(size_t)(n + 1) * NN + m] = row[1][m] * i1;
  }
}

// ---------------- K2: cg[b] = A @ c[b] (fp32) ----------------
__global__ __launch_bounds__(256) void k_gemm_Ac(const float* __restrict__ A,
                                                 const float* __restrict__ c,
                                                 float* __restrict__ cg) {
  __shared__ float At[64][68];
  __shared__ float cs[64][64];
  const int t = threadIdx.x;
  const int n0 = blockIdx.x * 64;
  const int b = blockIdx.y;
  const int tx = t & 15;
  const int ty = t >> 4;
  const float* cb = c + (size_t)b * NN * LL;
  float acc[4][4];
#pragma unroll
  for (int i = 0; i < 4; ++i)
#pragma unroll
    for (int j = 0; j < 4; ++j) acc[i][j] = 0.f;

  for (int k0 = 0; k0 < NN; k0 += 64) {
    __syncthreads();
#pragma unroll
    for (int rep = 0; rep < 4; ++rep) {
      int idx = t + rep * 256;
      int q = idx & 15;
      int r = idx >> 4;
      float4 av = *(const float4*)(A + (size_t)(n0 + r) * NN + k0 + 4 * q);
      At[4 * q + 0][r] = av.x;
      At[4 * q + 1][r] = av.y;
      At[4 * q + 2][r] = av.z;
      At[4 * q + 3][r] = av.w;
      float4 cv = *(const float4*)(cb + (size_t)(k0 + r) * LL + 4 * q);
      *(float4*)&cs[r][4 * q] = cv;
    }
    __syncthreads();
#pragma unroll 8
    for (int kk = 0; kk < 64; ++kk) {
      float4 av = *(const float4*)&At[kk][4 * ty];
      float4 cv = *(const float4*)&cs[kk][4 * tx];
      float a[4] = {av.x, av.y, av.z, av.w};
      float cc[4] = {cv.x, cv.y, cv.z, cv.w};
#pragma unroll
      for (int i = 0; i < 4; ++i)
#pragma unroll
        for (int j = 0; j < 4; ++j) acc[i][j] = fmaf(a[i], cc[j], acc[i][j]);
    }
  }
  float* outp = cg + ((size_t)b * NN + n0) * LL;
#pragma unroll
  for (int i = 0; i < 4; ++i) {
    float4 v = make_float4(acc[i][0], acc[i][1], acc[i][2], acc[i][3]);
    *(float4*)(outp + (size_t)(4 * ty + i) * LL + 4 * tx) = v;
  }
}

// ---------------- K3: ct = tanh(AGCRN combine) ----------------
__global__ __launch_bounds__(256) void k_gcn(const float* __restrict__ E,
                                             const float* __restrict__ Wp,
                                             const float* __restrict__ bp,
                                             const float* __restrict__ c,
                                             const float* __restrict__ cg,
                                             float* __restrict__ ct) {
  __shared__ float xs[4][2][BB][LL];
  __shared__ float Es[4][ADA];
  const int t = threadIdx.x;
  const int n0 = blockIdx.x * 4;
  const int o = t & 63;
  const int g = t >> 6;
  if (t < 4 * ADA) Es[t >> 4][t & 15] = E[(size_t)(n0 + (t >> 4)) * ADA + (t & 15)];
#pragma unroll
  for (int rep = 0; rep < 2; ++rep) {
    int idx = t + rep * 256;
    int q = idx & 15;
    int bb = (idx >> 4) & 7;
    int nl = idx >> 7;
    const size_t base = ((size_t)bb * NN + n0 + nl) * LL + 4 * q;
    *(float4*)&xs[nl][0][bb][4 * q] = *(const float4*)(c + base);
    *(float4*)&xs[nl][1][bb][4 * q] = *(const float4*)(cg + base);
  }
  __syncthreads();

  float acc[4][2];
#pragma unroll
  for (int nl = 0; nl < 4; ++nl) {
    float bnv = 0.f;
#pragma unroll
    for (int d = 0; d < ADA; ++d) bnv = fmaf(Es[nl][d], bp[d * LL + o], bnv);
    acc[nl][0] = bnv;
    acc[nl][1] = bnv;
  }
  for (int k = 0; k < 2; ++k) {
    for (int i = 0; i < LL; ++i) {
      float wd[ADA];
#pragma unroll
      for (int d = 0; d < ADA; ++d) wd[d] = Wp[(((size_t)d * 2 + k) * LL + i) * LL + o];
#pragma unroll
      for (int nl = 0; nl < 4; ++nl) {
        float w = 0.f;
#pragma unroll
        for (int d = 0; d < ADA; ++d) w = fmaf(Es[nl][d], wd[d], w);
        acc[nl][0] = fmaf(xs[nl][k][g][i], w, acc[nl][0]);
        acc[nl][1] = fmaf(xs[nl][k][g + 4][i], w, acc[nl][1]);
      }
    }
  }
#pragma unroll
  for (int nl = 0; nl < 4; ++nl) {
    ct[((size_t)g * NN + n0 + nl) * LL + o] = tanhf(acc[nl][0]);
    ct[((size_t)(g + 4) * NN + n0 + nl) * LL + o] = tanhf(acc[nl][1]);
  }
}

// ---------------- K4: prep — theta16[hb][n][16] (x0.5) and Vt16[hb][d][n] ----------------
__global__ __launch_bounds__(256) void k_prep(const float* __restrict__ state,
                                              const float* __restrict__ ct,
                                              unsigned short* __restrict__ th16,
                                              unsigned short* __restrict__ vt16) {
  __shared__ unsigned short vt[16][68];
  const int hb = blockIdx.x;
  const int h = hb >> 3, b = hb & 7;
  const int n0 = blockIdx.y * 64;
  const int t = threadIdx.x;
  const int r = t >> 2, dq = t & 3;
  const float* sp = state + ((size_t)b * NN + n0 + r) * LL + h * DH + 4 * dq;
  float4 sv = *(const float4*)sp;
  ushort4 tq = make_ushort4(f2bf(0.5f * sv.x), f2bf(0.5f * sv.y),
                            f2bf(0.5f * sv.z), f2bf(0.5f * sv.w));
  *(ushort4*)(th16 + ((size_t)hb * NN + n0 + r) * DH + 4 * dq) = tq;
  const float* cp = ct + ((size_t)b * NN + n0 + r) * LL + h * DH + 4 * dq;
  float4 cv = *(const float4*)cp;
  vt[4 * dq + 0][r] = f2bf(cv.x);
  vt[4 * dq + 1][r] = f2bf(cv.y);
  vt[4 * dq + 2][r] = f2bf(cv.z);
  vt[4 * dq + 3][r] = f2bf(cv.w);
  __syncthreads();
  const int d = t >> 4, mq = t & 15;
  ushort4 o = make_ushort4(vt[d][4 * mq + 0], vt[d][4 * mq + 1],
                           vt[d][4 * mq + 2], vt[d][4 * mq + 3]);
  *(ushort4*)(vt16 + ((size_t)hb * DH + d) * NN + n0 + 4 * mq) = o;
}

// ---------------- K5: MFMA attention, swapped-QK^T, no-shift softmax ----------------
__global__ __launch_bounds__(256) void k_attn2(const unsigned short* __restrict__ th16,
                                               const unsigned short* __restrict__ vt16,
                                               float* __restrict__ out) {
  const int hb = blockIdx.x;
  const int h = hb >> 3, b = hb & 7;
  const int wv = threadIdx.x >> 6, lane = threadIdx.x & 63;
  const int q0 = blockIdx.y * 64 + wv * 16;
  const int lr = lane & 15, lg = lane >> 4;
  const unsigned short* th = th16 + (size_t)hb * NN * DH;
  const unsigned short* vrow = vt16 + ((size_t)hb * DH + lr) * NN;  // V^T row d=lr
  // Q as B-operand: lane holds col q=lr, k d=4*lg+j  -> contiguous 8B
  bf16x4 qf = *(const bf16x4*)(th + (size_t)(q0 + lr) * DH + 4 * lg);
  const f32x4 zero = {0.f, 0.f, 0.f, 0.f};
  f32x4 acc = zero;
  float den = 0.f;
#pragma unroll 2
  for (int m0 = 0; m0 < NN; m0 += 16) {
    // K as A-operand: lane holds row m=m0+lr, k d=4*lg+j
    bf16x4 kf = *(const bf16x4*)(th + (size_t)(m0 + lr) * DH + 4 * lg);
    f32x4 s = MFMA16(kf, qf, zero);  // S^T tile: lane: col q=lr, rows m=m0+4*lg+j
    float p0 = __expf(s[0]), p1 = __expf(s[1]), p2 = __expf(s[2]), p3 = __expf(s[3]);
    den += (p0 + p1) + (p2 + p3);
    bf16x4 pf;
    pf[0] = (short)f2bf(p0); pf[1] = (short)f2bf(p1);
    pf[2] = (short)f2bf(p2); pf[3] = (short)f2bf(p3);
    // V^T as B-operand: lane holds col d=lr, k m=m0+4*lg+j -> contiguous 8B
    bf16x4 vf = *(const bf16x4*)(vrow + m0 + 4 * lg);
    acc = MFMA16(pf, vf, acc);  // out tile: lane: col d=lr, rows q=q0+4*lg+j
  }
  den += __shfl_xor(den, 16);
  den += __shfl_xor(den, 32);  // all lanes: den[q = lane&15]
  float* op = out + (size_t)b * NN * LL + h * DH + lr;
#pragma unroll
  for (int j = 0; j < 4; ++j) {
    const int qrow = 4 * lg + j;
    const float dq = __shfl(den, qrow);
    op[(size_t)(q0 + qrow) * LL] = -acc[j] / dq;
  }
}

extern "C" void kernel_launch(void* const* d_in, const int* in_sizes, int n_in,
                              void* d_out, int out_size, void* d_ws, size_t ws_size,
                              hipStream_t stream) {
  const float* c = (const float*)d_in[0];
  const float* state = (const float*)d_in[3];
  const float* E = (const float*)d_in[4];
  const float* Wp = (const float*)d_in[13];
  const float* bp = (const float*)d_in[14];
  float* out = (float*)d_out;

  float* A = (float*)d_ws;                      // 2048*2048 f32 = 16 MB
  float* cg = A + (size_t)NN * NN;              // 8*2048*64 f32 = 4 MB
  float* ctb = cg + (size_t)BB * NN * LL;       // 8*2048*64 f32 = 4 MB
  unsigned short* th16 = (unsigned short*)(ctb + (size_t)BB * NN * LL);  // 32*2048*16 bf16 = 2 MB
  unsigned short* vt16 = th16 + (size_t)HB * NN * DH;                    // 32*16*2048 bf16 = 2 MB

  k_rowsoftmax<<<NN / 2, 256, 0, stream>>>(E, A);
  k_gemm_Ac<<<dim3(NN / 64, BB), 256, 0, stream>>>(A, c, cg);
  k_gcn<<<NN / 4, 256, 0, stream>>>(E, Wp, bp, c, cg, ctb);
  k_prep<<<dim3(HB, NN / 64), 256, 0, stream>>>(state, ctb, th16, vt16);
  k_attn2<<<dim3(HB, NN / 64), 256, 0, stream>>>(th16, vt16, out);
}

// Round 4
// 171.004 us; speedup vs baseline: 1.9789x; 1.5449x over previous
//
#include <hip/hip_runtime.h>
#include <hip/hip_bf16.h>

#define NN 2048
#define BB 8
#define LL 64
#define ADA 16
#define DH 16
#define HB 32
#define KT 2048  // GCN GEMM total K = ADA*2*LL

typedef __attribute__((ext_vector_type(4))) short bf16x4;
typedef __attribute__((ext_vector_type(4))) float f32x4;
typedef __attribute__((ext_vector_type(8))) unsigned short ushort8v;

// __has_builtin(__builtin_amdgcn_mfma_*) is FALSE on the host pass of hipcc's
// dual compile -> guard with __HIP_DEVICE_COMPILE__, parse-only dummy on host.
#if defined(__HIP_DEVICE_COMPILE__)
#if __has_builtin(__builtin_amdgcn_mfma_f32_16x16x16bf16_1k)
#define MFMA16(a, b, c) __builtin_amdgcn_mfma_f32_16x16x16bf16_1k(a, b, c, 0, 0, 0)
#elif __has_builtin(__builtin_amdgcn_mfma_f32_16x16x16_bf16)
#define MFMA16(a, b, c) __builtin_amdgcn_mfma_f32_16x16x16_bf16(a, b, c, 0, 0, 0)
#else
#error "no 16x16x16 bf16 mfma builtin on device"
#endif
#else
#define MFMA16(a, b, c) (c)
#endif

__device__ inline unsigned short f2bf(float x) {
  __hip_bfloat16 h = __float2bfloat16(x);
  return *reinterpret_cast<unsigned short*>(&h);
}
__device__ inline float bf2f(unsigned short u) {
  unsigned int v = ((unsigned int)u) << 16;
  return *reinterpret_cast<float*>(&v);
}
__device__ inline void split2(float x, unsigned short& hi, unsigned short& lo) {
  unsigned short h = f2bf(x);
  hi = h;
  lo = f2bf(x - bf2f(h));
}

// ---------------- K1: A16 = bf16(rowsoftmax(relu(E E^T))), 2 rows/block ----------------
__global__ __launch_bounds__(256) void k_rowsoftmax(const float* __restrict__ E,
                                                    unsigned short* __restrict__ A16) {
  __shared__ float row[2][NN];
  __shared__ float red[2][256];
  const int n = blockIdx.x * 2;
  const int t = threadIdx.x;
  float4 e0[4], e1[4];
  const float4* E0 = (const float4*)(E + (size_t)n * ADA);
  const float4* E1 = (const float4*)(E + (size_t)(n + 1) * ADA);
#pragma unroll
  for (int j = 0; j < 4; ++j) { e0[j] = E0[j]; e1[j] = E1[j]; }
  float l0 = 0.f, l1 = 0.f;
  for (int m = t; m < NN; m += 256) {
    const float4* Em = (const float4*)(E + (size_t)m * ADA);
    float s0 = 0.f, s1 = 0.f;
#pragma unroll
    for (int j = 0; j < 4; ++j) {
      float4 ev = Em[j];
      s0 = fmaf(e0[j].x, ev.x, fmaf(e0[j].y, ev.y, fmaf(e0[j].z, ev.z, fmaf(e0[j].w, ev.w, s0))));
      s1 = fmaf(e1[j].x, ev.x, fmaf(e1[j].y, ev.y, fmaf(e1[j].z, ev.z, fmaf(e1[j].w, ev.w, s1))));
    }
    float p0 = __expf(fmaxf(s0, 0.f) - 20.f);  // fixed shift; cancels in normalize
    float p1 = __expf(fmaxf(s1, 0.f) - 20.f);
    row[0][m] = p0; row[1][m] = p1;
    l0 += p0; l1 += p1;
  }
  red[0][t] = l0; red[1][t] = l1;
  __syncthreads();
  for (int off = 128; off > 0; off >>= 1) {
    if (t < off) { red[0][t] += red[0][t + off]; red[1][t] += red[1][t + off]; }
    __syncthreads();
  }
  const float i0 = 1.f / red[0][0], i1 = 1.f / red[1][0];
  for (int m = t; m < NN; m += 256) {
    A16[(size_t)n * NN + m] = f2bf(row[0][m] * i0);
    A16[(size_t)(n + 1) * NN + m] = f2bf(row[1][m] * i1);
  }
}

// ---------------- K2a: cT16[b][o][m] = bf16(c[b][m][o]) ----------------
__global__ __launch_bounds__(256) void k_prep_c(const float* __restrict__ c,
                                                unsigned short* __restrict__ cT16) {
  __shared__ float ld[64][68];
  const int m0 = blockIdx.x * 64;
  const int b = blockIdx.y;
  const int t = threadIdx.x;
  {
    const int r = t & 63, cq = t >> 6;
    const float* cp = c + ((size_t)b * NN + m0 + r) * LL + cq * 16;
#pragma unroll
    for (int u = 0; u < 4; ++u)
      *(float4*)&ld[r][cq * 16 + 4 * u] = *(const float4*)(cp + 4 * u);
  }
  __syncthreads();
  const int o = t & 63, mq = t >> 6;
  unsigned short outv[16];
#pragma unroll
  for (int v = 0; v < 16; ++v) outv[v] = f2bf(ld[mq * 16 + v][o]);
  unsigned short* op = cT16 + ((size_t)b * LL + o) * NN + m0 + mq * 16;
  *(ushort8v*)op = *(const ushort8v*)&outv[0];
  *(ushort8v*)(op + 8) = *(const ushort8v*)&outv[8];
}

// ---------------- K2b: WpT hi/lo [o][k], k=(d,kk,i) ----------------
__global__ __launch_bounds__(256) void k_prep_w(const float* __restrict__ Wp,
                                                unsigned short* __restrict__ WpTh,
                                                unsigned short* __restrict__ WpTl) {
  __shared__ float ld[64][68];
  const int k0 = blockIdx.x * 64;
  const int t = threadIdx.x;
  {
    const int r = t & 63, cq = t >> 6;
    const float* wp = Wp + (size_t)(k0 + r) * LL + cq * 16;
#pragma unroll
    for (int u = 0; u < 4; ++u)
      *(float4*)&ld[r][cq * 16 + 4 * u] = *(const float4*)(wp + 4 * u);
  }
  __syncthreads();
  const int o = t & 63, kq = t >> 6;
  unsigned short hv[16], lv[16];
#pragma unroll
  for (int v = 0; v < 16; ++v) split2(ld[kq * 16 + v][o], hv[v], lv[v]);
  const size_t off = (size_t)o * KT + k0 + kq * 16;
  *(ushort8v*)(WpTh + off) = *(const ushort8v*)&hv[0];
  *(ushort8v*)(WpTh + off + 8) = *(const ushort8v*)&hv[8];
  *(ushort8v*)(WpTl + off) = *(const ushort8v*)&lv[0];
  *(ushort8v*)(WpTl + off + 8) = *(const ushort8v*)&lv[8];
}

// ---------------- K3: cg[b] = A @ c[b], bf16 MFMA ----------------
__global__ __launch_bounds__(256) void k_gemm1(const unsigned short* __restrict__ A16,
                                               const unsigned short* __restrict__ cT16,
                                               float* __restrict__ cg) {
  __shared__ unsigned short sA[64][72];
  __shared__ unsigned short sB[64][72];
  const int t = threadIdx.x;
  const int n0 = blockIdx.x * 64;
  const int b = blockIdx.y;
  const int wv = t >> 6, lane = t & 63;
  const int lr = lane & 15, lg = lane >> 4;
  const unsigned short* cb = cT16 + (size_t)b * LL * NN;
  const int sr = t >> 2, sc = (t & 3) * 16;
  f32x4 acc[4];
#pragma unroll
  for (int ot = 0; ot < 4; ++ot) acc[ot] = (f32x4){0.f, 0.f, 0.f, 0.f};

  for (int k0 = 0; k0 < NN; k0 += 64) {
    __syncthreads();
    {
      const unsigned short* ga = A16 + (size_t)(n0 + sr) * NN + k0 + sc;
      *(ushort8v*)&sA[sr][sc] = *(const ushort8v*)ga;
      *(ushort8v*)&sA[sr][sc + 8] = *(const ushort8v*)(ga + 8);
      const unsigned short* gb = cb + (size_t)sr * NN + k0 + sc;
      *(ushort8v*)&sB[sr][sc] = *(const ushort8v*)gb;
      *(ushort8v*)&sB[sr][sc + 8] = *(const ushort8v*)(gb + 8);
    }
    __syncthreads();
#pragma unroll
    for (int ks = 0; ks < 4; ++ks) {
      bf16x4 a = *(const bf16x4*)&sA[16 * wv + lr][ks * 16 + 4 * lg];
#pragma unroll
      for (int ot = 0; ot < 4; ++ot) {
        bf16x4 bq = *(const bf16x4*)&sB[ot * 16 + lr][ks * 16 + 4 * lg];
        acc[ot] = MFMA16(a, bq, acc[ot]);
      }
    }
  }
  float* outp = cg + ((size_t)b * NN + n0 + 16 * wv) * LL;
#pragma unroll
  for (int ot = 0; ot < 4; ++ot)
#pragma unroll
    for (int reg = 0; reg < 4; ++reg)
      outp[(size_t)(4 * lg + reg) * LL + ot * 16 + lr] = acc[ot][reg];
}

// ---------------- K4: ct = tanh(sum_d E[n,d]*(xg @ Wp[d]) + E@bp), split-bf16 MFMA ----------------
__global__ __launch_bounds__(256) void k_gcn2(const float* __restrict__ E,
                                              const unsigned short* __restrict__ WpTh,
                                              const unsigned short* __restrict__ WpTl,
                                              const float* __restrict__ bp,
                                              const float* __restrict__ c,
                                              const float* __restrict__ cg,
                                              float* __restrict__ ct) {
  __shared__ unsigned short sXh[2][64][72];
  __shared__ unsigned short sXl[2][64][72];
  __shared__ unsigned short sBh[64][72];
  __shared__ unsigned short sBl[64][72];
  __shared__ float sE[64][16];
  const int t = threadIdx.x;
  const int n0 = blockIdx.x * 64;
  const int b = blockIdx.y;
  const int wv = t >> 6, lane = t & 63;
  const int lr = lane & 15, lg = lane >> 4;
  {
    const int r = t >> 2, dq = (t & 3) * 4;
    *(float4*)&sE[r][dq] = *(const float4*)(E + (size_t)(n0 + r) * ADA + dq);
  }
  {
    const int r = t >> 2, i0 = (t & 3) * 16;
    const float* cp = c + ((size_t)b * NN + n0 + r) * LL + i0;
    const float* gp = cg + ((size_t)b * NN + n0 + r) * LL + i0;
#pragma unroll
    for (int u = 0; u < 4; ++u) {
      float4 cv = *(const float4*)(cp + 4 * u);
      float4 gv = *(const float4*)(gp + 4 * u);
      ushort4 ch, cl, gh, gl;
      split2(cv.x, ch.x, cl.x); split2(cv.y, ch.y, cl.y);
      split2(cv.z, ch.z, cl.z); split2(cv.w, ch.w, cl.w);
      split2(gv.x, gh.x, gl.x); split2(gv.y, gh.y, gl.y);
      split2(gv.z, gh.z, gl.z); split2(gv.w, gh.w, gl.w);
      *(ushort4*)&sXh[0][r][i0 + 4 * u] = ch;
      *(ushort4*)&sXl[0][r][i0 + 4 * u] = cl;
      *(ushort4*)&sXh[1][r][i0 + 4 * u] = gh;
      *(ushort4*)&sXl[1][r][i0 + 4 * u] = gl;
    }
  }
  __syncthreads();
  const int row0 = 16 * wv + 4 * lg;
  f32x4 acc[4];
#pragma unroll
  for (int ot = 0; ot < 4; ++ot) {
    const int o = ot * 16 + lr;
#pragma unroll
    for (int reg = 0; reg < 4; ++reg) {
      float s = 0.f;
#pragma unroll
      for (int d = 0; d < ADA; ++d) s = fmaf(sE[row0 + reg][d], bp[d * LL + o], s);
      acc[ot][reg] = s;
    }
  }
  const int so = t >> 2, sc = (t & 3) * 16;
  for (int d = 0; d < ADA; ++d) {
    f32x4 p[4];
#pragma unroll
    for (int ot = 0; ot < 4; ++ot) p[ot] = (f32x4){0.f, 0.f, 0.f, 0.f};
    for (int kk = 0; kk < 2; ++kk) {
      __syncthreads();
      {
        const size_t gof = (size_t)so * KT + d * 128 + kk * 64 + sc;
        *(ushort8v*)&sBh[so][sc] = *(const ushort8v*)(WpTh + gof);
        *(ushort8v*)&sBh[so][sc + 8] = *(const ushort8v*)(WpTh + gof + 8);
        *(ushort8v*)&sBl[so][sc] = *(const ushort8v*)(WpTl + gof);
        *(ushort8v*)&sBl[so][sc + 8] = *(const ushort8v*)(WpTl + gof + 8);
      }
      __syncthreads();
#pragma unroll
      for (int ks = 0; ks < 4; ++ks) {
        bf16x4 aH = *(const bf16x4*)&sXh[kk][16 * wv + lr][ks * 16 + 4 * lg];
        bf16x4 aL = *(const bf16x4*)&sXl[kk][16 * wv + lr][ks * 16 + 4 * lg];
#pragma unroll
        for (int ot = 0; ot < 4; ++ot) {
          bf16x4 bH = *(const bf16x4*)&sBh[ot * 16 + lr][ks * 16 + 4 * lg];
          bf16x4 bL = *(const bf16x4*)&sBl[ot * 16 + lr][ks * 16 + 4 * lg];
          p[ot] = MFMA16(aH, bH, p[ot]);
          p[ot] = MFMA16(aH, bL, p[ot]);
          p[ot] = MFMA16(aL, bH, p[ot]);
        }
      }
    }
    const float e0 = sE[row0 + 0][d], e1 = sE[row0 + 1][d];
    const float e2 = sE[row0 + 2][d], e3 = sE[row0 + 3][d];
#pragma unroll
    for (int ot = 0; ot < 4; ++ot) {
      acc[ot][0] = fmaf(e0, p[ot][0], acc[ot][0]);
      acc[ot][1] = fmaf(e1, p[ot][1], acc[ot][1]);
      acc[ot][2] = fmaf(e2, p[ot][2], acc[ot][2]);
      acc[ot][3] = fmaf(e3, p[ot][3], acc[ot][3]);
    }
  }
  float* outp = ct + ((size_t)b * NN + n0 + 16 * wv) * LL;
#pragma unroll
  for (int ot = 0; ot < 4; ++ot)
#pragma unroll
    for (int reg = 0; reg < 4; ++reg) {
      const float v = acc[ot][reg];
      const float tv = 1.f - 2.f / (__expf(2.f * v) + 1.f);  // tanh
      outp[(size_t)(4 * lg + reg) * LL + ot * 16 + lr] = tv;
    }
}

// ---------------- K5: prep — theta16[hb][n][16] (x0.5) and Vt16[hb][d][n] ----------------
__global__ __launch_bounds__(256) void k_prep(const float* __restrict__ state,
                                              const float* __restrict__ ct,
                                              unsigned short* __restrict__ th16,
                                              unsigned short* __restrict__ vt16) {
  __shared__ unsigned short vt[16][68];
  const int hb = blockIdx.x;
  const int h = hb >> 3, b = hb & 7;
  const int n0 = blockIdx.y * 64;
  const int t = threadIdx.x;
  const int r = t >> 2, dq = t & 3;
  const float* sp = state + ((size_t)b * NN + n0 + r) * LL + h * DH + 4 * dq;
  float4 sv = *(const float4*)sp;
  ushort4 tq = make_ushort4(f2bf(0.5f * sv.x), f2bf(0.5f * sv.y),
                            f2bf(0.5f * sv.z), f2bf(0.5f * sv.w));
  *(ushort4*)(th16 + ((size_t)hb * NN + n0 + r) * DH + 4 * dq) = tq;
  const float* cp = ct + ((size_t)b * NN + n0 + r) * LL + h * DH + 4 * dq;
  float4 cv = *(const float4*)cp;
  vt[4 * dq + 0][r] = f2bf(cv.x);
  vt[4 * dq + 1][r] = f2bf(cv.y);
  vt[4 * dq + 2][r] = f2bf(cv.z);
  vt[4 * dq + 3][r] = f2bf(cv.w);
  __syncthreads();
  const int d = t >> 4, mq = t & 15;
  ushort4 o = make_ushort4(vt[d][4 * mq + 0], vt[d][4 * mq + 1],
                           vt[d][4 * mq + 2], vt[d][4 * mq + 3]);
  *(ushort4*)(vt16 + ((size_t)hb * DH + d) * NN + n0 + 4 * mq) = o;
}

// ---------------- K6: MFMA attention, swapped-QK^T, no-shift softmax ----------------
__global__ __launch_bounds__(256) void k_attn2(const unsigned short* __restrict__ th16,
                                               const unsigned short* __restrict__ vt16,
                                               float* __restrict__ out) {
  const int hb = blockIdx.x;
  const int h = hb >> 3, b = hb & 7;
  const int wv = threadIdx.x >> 6, lane = threadIdx.x & 63;
  const int q0 = blockIdx.y * 64 + wv * 16;
  const int lr = lane & 15, lg = lane >> 4;
  const unsigned short* th = th16 + (size_t)hb * NN * DH;
  const unsigned short* vrow = vt16 + ((size_t)hb * DH + lr) * NN;
  bf16x4 qf = *(const bf16x4*)(th + (size_t)(q0 + lr) * DH + 4 * lg);
  const f32x4 zero = {0.f, 0.f, 0.f, 0.f};
  f32x4 acc = zero;
  float den = 0.f;
#pragma unroll 2
  for (int m0 = 0; m0 < NN; m0 += 16) {
    bf16x4 kf = *(const bf16x4*)(th + (size_t)(m0 + lr) * DH + 4 * lg);
    f32x4 s = MFMA16(kf, qf, zero);
    float p0 = __expf(s[0]), p1 = __expf(s[1]), p2 = __expf(s[2]), p3 = __expf(s[3]);
    den += (p0 + p1) + (p2 + p3);
    bf16x4 pf;
    pf[0] = (short)f2bf(p0); pf[1] = (short)f2bf(p1);
    pf[2] = (short)f2bf(p2); pf[3] = (short)f2bf(p3);
    bf16x4 vf = *(const bf16x4*)(vrow + m0 + 4 * lg);
    acc = MFMA16(pf, vf, acc);
  }
  den += __shfl_xor(den, 16);
  den += __shfl_xor(den, 32);
  float* op = out + (size_t)b * NN * LL + h * DH + lr;
#pragma unroll
  for (int j = 0; j < 4; ++j) {
    const int qrow = 4 * lg + j;
    const float dq = __shfl(den, qrow);
    op[(size_t)(q0 + qrow) * LL] = -acc[j] / dq;
  }
}

extern "C" void kernel_launch(void* const* d_in, const int* in_sizes, int n_in,
                              void* d_out, int out_size, void* d_ws, size_t ws_size,
                              hipStream_t stream) {
  const float* c = (const float*)d_in[0];
  const float* state = (const float*)d_in[3];
  const float* E = (const float*)d_in[4];
  const float* Wp = (const float*)d_in[13];
  const float* bp = (const float*)d_in[14];
  float* out = (float*)d_out;

  unsigned short* A16 = (unsigned short*)d_ws;        // 2048*2048 bf16 = 8 MB
  unsigned short* cT16 = A16 + (size_t)NN * NN;       // 8*64*2048 = 2 MB
  unsigned short* WpTh = cT16 + (size_t)BB * LL * NN; // 64*2048 = 256 KB
  unsigned short* WpTl = WpTh + (size_t)LL * KT;      // 256 KB
  float* cg = (float*)(WpTl + (size_t)LL * KT);       // 8*2048*64 f32 = 4 MB
  float* ctb = cg + (size_t)BB * NN * LL;             // 4 MB
  unsigned short* th16 = (unsigned short*)(ctb + (size_t)BB * NN * LL);  // 2 MB
  unsigned short* vt16 = th16 + (size_t)HB * NN * DH;                    // 2 MB

  k_rowsoftmax<<<NN / 2, 256, 0, stream>>>(E, A16);
  k_prep_c<<<dim3(NN / 64, BB), 256, 0, stream>>>(c, cT16);
  k_prep_w<<<KT / 64, 256, 0, stream>>>(Wp, WpTh, WpTl);
  k_gemm1<<<dim3(NN / 64, BB), 256, 0, stream>>>(A16, cT16, cg);
  k_gcn2<<<dim3(NN / 64, BB), 256, 0, stream>>>(E, WpTh, WpTl, bp, c, cg, ctb);
  k_prep<<<dim3(HB, NN / 64), 256, 0, stream>>>(state, ctb, th16, vt16);
  k_attn2<<<dim3(HB, NN / 64), 256, 0, stream>>>(th16, vt16, out);
}

// Round 5
// 129.702 us; speedup vs baseline: 2.6090x; 1.3184x over previous
//
#include <hip/hip_runtime.h>
#include <hip/hip_bf16.h>

#define NN 2048
#define BB 8
#define LL 64
#define ADA 16
#define DH 16
#define HB 32
#define KT 2048  // GCN GEMM total K = ADA*2*LL

typedef __attribute__((ext_vector_type(4))) short bf16x4;
typedef __attribute__((ext_vector_type(4))) float f32x4;
typedef __attribute__((ext_vector_type(8))) unsigned short ushort8v;

// __has_builtin(__builtin_amdgcn_mfma_*) is FALSE on the host pass of hipcc's
// dual compile -> guard with __HIP_DEVICE_COMPILE__, parse-only dummy on host.
#if defined(__HIP_DEVICE_COMPILE__)
#if __has_builtin(__builtin_amdgcn_mfma_f32_16x16x16bf16_1k)
#define MFMA16(a, b, c) __builtin_amdgcn_mfma_f32_16x16x16bf16_1k(a, b, c, 0, 0, 0)
#elif __has_builtin(__builtin_amdgcn_mfma_f32_16x16x16_bf16)
#define MFMA16(a, b, c) __builtin_amdgcn_mfma_f32_16x16x16_bf16(a, b, c, 0, 0, 0)
#else
#error "no 16x16x16 bf16 mfma builtin on device"
#endif
#if __has_builtin(__builtin_amdgcn_exp2f)
#define EXP2F(x) __builtin_amdgcn_exp2f(x)
#else
#define EXP2F(x) exp2f(x)
#endif
#else
#define MFMA16(a, b, c) (c)
#define EXP2F(x) exp2f(x)
#endif

__device__ inline unsigned short f2bf(float x) {
  __hip_bfloat16 h = __float2bfloat16(x);
  return *reinterpret_cast<unsigned short*>(&h);
}
__device__ inline float bf2f(unsigned short u) {
  unsigned int v = ((unsigned int)u) << 16;
  return *reinterpret_cast<float*>(&v);
}
__device__ inline void split2(float x, unsigned short& hi, unsigned short& lo) {
  unsigned short h = f2bf(x);
  hi = h;
  lo = f2bf(x - bf2f(h));
}

// ---------------- K1: A16 = bf16(rowsoftmax(relu(E E^T))), 2 rows/block ----------------
__global__ __launch_bounds__(256) void k_rowsoftmax(const float* __restrict__ E,
                                                    unsigned short* __restrict__ A16) {
  __shared__ float row[2][NN];
  __shared__ float red[2][256];
  const int n = blockIdx.x * 2;
  const int t = threadIdx.x;
  float4 e0[4], e1[4];
  const float4* E0 = (const float4*)(E + (size_t)n * ADA);
  const float4* E1 = (const float4*)(E + (size_t)(n + 1) * ADA);
#pragma unroll
  for (int j = 0; j < 4; ++j) { e0[j] = E0[j]; e1[j] = E1[j]; }
  float l0 = 0.f, l1 = 0.f;
  for (int m = t; m < NN; m += 256) {
    const float4* Em = (const float4*)(E + (size_t)m * ADA);
    float s0 = 0.f, s1 = 0.f;
#pragma unroll
    for (int j = 0; j < 4; ++j) {
      float4 ev = Em[j];
      s0 = fmaf(e0[j].x, ev.x, fmaf(e0[j].y, ev.y, fmaf(e0[j].z, ev.z, fmaf(e0[j].w, ev.w, s0))));
      s1 = fmaf(e1[j].x, ev.x, fmaf(e1[j].y, ev.y, fmaf(e1[j].z, ev.z, fmaf(e1[j].w, ev.w, s1))));
    }
    float p0 = __expf(fmaxf(s0, 0.f) - 20.f);  // fixed shift; cancels in normalize
    float p1 = __expf(fmaxf(s1, 0.f) - 20.f);
    row[0][m] = p0; row[1][m] = p1;
    l0 += p0; l1 += p1;
  }
  red[0][t] = l0; red[1][t] = l1;
  __syncthreads();
  for (int off = 128; off > 0; off >>= 1) {
    if (t < off) { red[0][t] += red[0][t + off]; red[1][t] += red[1][t + off]; }
    __syncthreads();
  }
  const float i0 = 1.f / red[0][0], i1 = 1.f / red[1][0];
  for (int m = t; m < NN; m += 256) {
    A16[(size_t)n * NN + m] = f2bf(row[0][m] * i0);
    A16[(size_t)(n + 1) * NN + m] = f2bf(row[1][m] * i1);
  }
}

// ---------------- K2a: cT16[b][o][m] = bf16(c[b][m][o]) ----------------
__global__ __launch_bounds__(256) void k_prep_c(const float* __restrict__ c,
                                                unsigned short* __restrict__ cT16) {
  __shared__ float ld[64][68];
  const int m0 = blockIdx.x * 64;
  const int b = blockIdx.y;
  const int t = threadIdx.x;
  {
    const int r = t & 63, cq = t >> 6;
    const float* cp = c + ((size_t)b * NN + m0 + r) * LL + cq * 16;
#pragma unroll
    for (int u = 0; u < 4; ++u)
      *(float4*)&ld[r][cq * 16 + 4 * u] = *(const float4*)(cp + 4 * u);
  }
  __syncthreads();
  const int o = t & 63, mq = t >> 6;
  unsigned short outv[16];
#pragma unroll
  for (int v = 0; v < 16; ++v) outv[v] = f2bf(ld[mq * 16 + v][o]);
  unsigned short* op = cT16 + ((size_t)b * LL + o) * NN + m0 + mq * 16;
  *(ushort8v*)op = *(const ushort8v*)&outv[0];
  *(ushort8v*)(op + 8) = *(const ushort8v*)&outv[8];
}

// ---------------- K2b: WpT hi/lo [o][k], k=(d,kk,i) ----------------
__global__ __launch_bounds__(256) void k_prep_w(const float* __restrict__ Wp,
                                                unsigned short* __restrict__ WpTh,
                                                unsigned short* __restrict__ WpTl) {
  __shared__ float ld[64][68];
  const int k0 = blockIdx.x * 64;
  const int t = threadIdx.x;
  {
    const int r = t & 63, cq = t >> 6;
    const float* wp = Wp + (size_t)(k0 + r) * LL + cq * 16;
#pragma unroll
    for (int u = 0; u < 4; ++u)
      *(float4*)&ld[r][cq * 16 + 4 * u] = *(const float4*)(wp + 4 * u);
  }
  __syncthreads();
  const int o = t & 63, kq = t >> 6;
  unsigned short hv[16], lv[16];
#pragma unroll
  for (int v = 0; v < 16; ++v) split2(ld[kq * 16 + v][o], hv[v], lv[v]);
  const size_t off = (size_t)o * KT + k0 + kq * 16;
  *(ushort8v*)(WpTh + off) = *(const ushort8v*)&hv[0];
  *(ushort8v*)(WpTh + off + 8) = *(const ushort8v*)&hv[8];
  *(ushort8v*)(WpTl + off) = *(const ushort8v*)&lv[0];
  *(ushort8v*)(WpTl + off + 8) = *(const ushort8v*)&lv[8];
}

// ---------------- K3: cg[b] = A @ c[b], bf16 MFMA ----------------
__global__ __launch_bounds__(256) void k_gemm1(const unsigned short* __restrict__ A16,
                                               const unsigned short* __restrict__ cT16,
                                               float* __restrict__ cg) {
  __shared__ unsigned short sA[64][72];
  __shared__ unsigned short sB[64][72];
  const int t = threadIdx.x;
  const int n0 = blockIdx.x * 64;
  const int b = blockIdx.y;
  const int wv = t >> 6, lane = t & 63;
  const int lr = lane & 15, lg = lane >> 4;
  const unsigned short* cb = cT16 + (size_t)b * LL * NN;
  const int sr = t >> 2, sc = (t & 3) * 16;
  f32x4 acc[4];
#pragma unroll
  for (int ot = 0; ot < 4; ++ot) acc[ot] = (f32x4){0.f, 0.f, 0.f, 0.f};

  for (int k0 = 0; k0 < NN; k0 += 64) {
    __syncthreads();
    {
      const unsigned short* ga = A16 + (size_t)(n0 + sr) * NN + k0 + sc;
      *(ushort8v*)&sA[sr][sc] = *(const ushort8v*)ga;
      *(ushort8v*)&sA[sr][sc + 8] = *(const ushort8v*)(ga + 8);
      const unsigned short* gb = cb + (size_t)sr * NN + k0 + sc;
      *(ushort8v*)&sB[sr][sc] = *(const ushort8v*)gb;
      *(ushort8v*)&sB[sr][sc + 8] = *(const ushort8v*)(gb + 8);
    }
    __syncthreads();
#pragma unroll
    for (int ks = 0; ks < 4; ++ks) {
      bf16x4 a = *(const bf16x4*)&sA[16 * wv + lr][ks * 16 + 4 * lg];
#pragma unroll
      for (int ot = 0; ot < 4; ++ot) {
        bf16x4 bq = *(const bf16x4*)&sB[ot * 16 + lr][ks * 16 + 4 * lg];
        acc[ot] = MFMA16(a, bq, acc[ot]);
      }
    }
  }
  float* outp = cg + ((size_t)b * NN + n0 + 16 * wv) * LL;
#pragma unroll
  for (int ot = 0; ot < 4; ++ot)
#pragma unroll
    for (int reg = 0; reg < 4; ++reg)
      outp[(size_t)(4 * lg + reg) * LL + ot * 16 + lr] = acc[ot][reg];
}

// ---------------- K4: ct = tanh(sum_d E[n,d]*(xg @ Wp[d]) + E@bp), split-bf16 MFMA ----------------
__global__ __launch_bounds__(256) void k_gcn2(const float* __restrict__ E,
                                              const unsigned short* __restrict__ WpTh,
                                              const unsigned short* __restrict__ WpTl,
                                              const float* __restrict__ bp,
                                              const float* __restrict__ c,
                                              const float* __restrict__ cg,
                                              float* __restrict__ ct) {
  __shared__ unsigned short sXh[2][64][72];
  __shared__ unsigned short sXl[2][64][72];
  __shared__ unsigned short sBh[64][72];
  __shared__ unsigned short sBl[64][72];
  __shared__ float sE[64][16];
  const int t = threadIdx.x;
  const int n0 = blockIdx.x * 64;
  const int b = blockIdx.y;
  const int wv = t >> 6, lane = t & 63;
  const int lr = lane & 15, lg = lane >> 4;
  {
    const int r = t >> 2, dq = (t & 3) * 4;
    *(float4*)&sE[r][dq] = *(const float4*)(E + (size_t)(n0 + r) * ADA + dq);
  }
  {
    const int r = t >> 2, i0 = (t & 3) * 16;
    const float* cp = c + ((size_t)b * NN + n0 + r) * LL + i0;
    const float* gp = cg + ((size_t)b * NN + n0 + r) * LL + i0;
#pragma unroll
    for (int u = 0; u < 4; ++u) {
      float4 cv = *(const float4*)(cp + 4 * u);
      float4 gv = *(const float4*)(gp + 4 * u);
      ushort4 ch, cl, gh, gl;
      split2(cv.x, ch.x, cl.x); split2(cv.y, ch.y, cl.y);
      split2(cv.z, ch.z, cl.z); split2(cv.w, ch.w, cl.w);
      split2(gv.x, gh.x, gl.x); split2(gv.y, gh.y, gl.y);
      split2(gv.z, gh.z, gl.z); split2(gv.w, gh.w, gl.w);
      *(ushort4*)&sXh[0][r][i0 + 4 * u] = ch;
      *(ushort4*)&sXl[0][r][i0 + 4 * u] = cl;
      *(ushort4*)&sXh[1][r][i0 + 4 * u] = gh;
      *(ushort4*)&sXl[1][r][i0 + 4 * u] = gl;
    }
  }
  __syncthreads();
  const int row0 = 16 * wv + 4 * lg;
  f32x4 acc[4];
#pragma unroll
  for (int ot = 0; ot < 4; ++ot) {
    const int o = ot * 16 + lr;
#pragma unroll
    for (int reg = 0; reg < 4; ++reg) {
      float s = 0.f;
#pragma unroll
      for (int d = 0; d < ADA; ++d) s = fmaf(sE[row0 + reg][d], bp[d * LL + o], s);
      acc[ot][reg] = s;
    }
  }
  const int so = t >> 2, sc = (t & 3) * 16;
  for (int d = 0; d < ADA; ++d) {
    f32x4 p[4];
#pragma unroll
    for (int ot = 0; ot < 4; ++ot) p[ot] = (f32x4){0.f, 0.f, 0.f, 0.f};
    for (int kk = 0; kk < 2; ++kk) {
      __syncthreads();
      {
        const size_t gof = (size_t)so * KT + d * 128 + kk * 64 + sc;
        *(ushort8v*)&sBh[so][sc] = *(const ushort8v*)(WpTh + gof);
        *(ushort8v*)&sBh[so][sc + 8] = *(const ushort8v*)(WpTh + gof + 8);
        *(ushort8v*)&sBl[so][sc] = *(const ushort8v*)(WpTl + gof);
        *(ushort8v*)&sBl[so][sc + 8] = *(const ushort8v*)(WpTl + gof + 8);
      }
      __syncthreads();
#pragma unroll
      for (int ks = 0; ks < 4; ++ks) {
        bf16x4 aH = *(const bf16x4*)&sXh[kk][16 * wv + lr][ks * 16 + 4 * lg];
        bf16x4 aL = *(const bf16x4*)&sXl[kk][16 * wv + lr][ks * 16 + 4 * lg];
#pragma unroll
        for (int ot = 0; ot < 4; ++ot) {
          bf16x4 bH = *(const bf16x4*)&sBh[ot * 16 + lr][ks * 16 + 4 * lg];
          bf16x4 bL = *(const bf16x4*)&sBl[ot * 16 + lr][ks * 16 + 4 * lg];
          p[ot] = MFMA16(aH, bH, p[ot]);
          p[ot] = MFMA16(aH, bL, p[ot]);
          p[ot] = MFMA16(aL, bH, p[ot]);
        }
      }
    }
    const float e0 = sE[row0 + 0][d], e1 = sE[row0 + 1][d];
    const float e2 = sE[row0 + 2][d], e3 = sE[row0 + 3][d];
#pragma unroll
    for (int ot = 0; ot < 4; ++ot) {
      acc[ot][0] = fmaf(e0, p[ot][0], acc[ot][0]);
      acc[ot][1] = fmaf(e1, p[ot][1], acc[ot][1]);
      acc[ot][2] = fmaf(e2, p[ot][2], acc[ot][2]);
      acc[ot][3] = fmaf(e3, p[ot][3], acc[ot][3]);
    }
  }
  float* outp = ct + ((size_t)b * NN + n0 + 16 * wv) * LL;
#pragma unroll
  for (int ot = 0; ot < 4; ++ot)
#pragma unroll
    for (int reg = 0; reg < 4; ++reg) {
      const float v = acc[ot][reg];
      const float tv = 1.f - 2.f / (__expf(2.f * v) + 1.f);  // tanh
      outp[(size_t)(4 * lg + reg) * LL + ot * 16 + lr] = tv;
    }
}

// ---------------- K5: prep — th16 (K, x1), thq16 (Q, x0.25*log2e), Vt16 ----------------
__global__ __launch_bounds__(256) void k_prep(const float* __restrict__ state,
                                              const float* __restrict__ ct,
                                              unsigned short* __restrict__ th16,
                                              unsigned short* __restrict__ thq16,
                                              unsigned short* __restrict__ vt16) {
  __shared__ unsigned short vt[16][68];
  const int hb = blockIdx.x;
  const int h = hb >> 3, b = hb & 7;
  const int n0 = blockIdx.y * 64;
  const int t = threadIdx.x;
  const int r = t >> 2, dq = t & 3;
  const float QS = 0.25f * 1.4426950408889634f;  // fold 1/sqrt(16) pair + log2(e) into Q
  const float* sp = state + ((size_t)b * NN + n0 + r) * LL + h * DH + 4 * dq;
  float4 sv = *(const float4*)sp;
  ushort4 tk = make_ushort4(f2bf(sv.x), f2bf(sv.y), f2bf(sv.z), f2bf(sv.w));
  *(ushort4*)(th16 + ((size_t)hb * NN + n0 + r) * DH + 4 * dq) = tk;
  ushort4 tq = make_ushort4(f2bf(QS * sv.x), f2bf(QS * sv.y),
                            f2bf(QS * sv.z), f2bf(QS * sv.w));
  *(ushort4*)(thq16 + ((size_t)hb * NN + n0 + r) * DH + 4 * dq) = tq;
  const float* cp = ct + ((size_t)b * NN + n0 + r) * LL + h * DH + 4 * dq;
  float4 cv = *(const float4*)cp;
  vt[4 * dq + 0][r] = f2bf(cv.x);
  vt[4 * dq + 1][r] = f2bf(cv.y);
  vt[4 * dq + 2][r] = f2bf(cv.z);
  vt[4 * dq + 3][r] = f2bf(cv.w);
  __syncthreads();
  const int d = t >> 4, mq = t & 15;
  ushort4 o = make_ushort4(vt[d][4 * mq + 0], vt[d][4 * mq + 1],
                           vt[d][4 * mq + 2], vt[d][4 * mq + 3]);
  *(ushort4*)(vt16 + ((size_t)hb * DH + d) * NN + n0 + 4 * mq) = o;
}

// ---------------- K6: MFMA attention — 64 q/wave (4 frags), split-m across 4 waves ----------------
__global__ __launch_bounds__(256) void k_attn3(const unsigned short* __restrict__ th16,
                                               const unsigned short* __restrict__ thq16,
                                               const unsigned short* __restrict__ vt16,
                                               float* __restrict__ out) {
  __shared__ float dnum[4][4][16][16];  // [wave][frag][qrow][d]
  __shared__ float dden[4][4][16];      // [wave][frag][q]
  const int hb = blockIdx.x;
  const int h = hb >> 3, b = hb & 7;
  const int wv = threadIdx.x >> 6, lane = threadIdx.x & 63;
  const int q0 = blockIdx.y * 64;
  const int lr = lane & 15, lg = lane >> 4;
  const unsigned short* th = th16 + (size_t)hb * NN * DH;
  const unsigned short* thq = thq16 + (size_t)hb * NN * DH;
  const unsigned short* vrow = vt16 + ((size_t)hb * DH + lr) * NN;  // V^T row d=lr
  bf16x4 qf[4];
#pragma unroll
  for (int f = 0; f < 4; ++f)
    qf[f] = *(const bf16x4*)(thq + (size_t)(q0 + 16 * f + lr) * DH + 4 * lg);
  const f32x4 zero = {0.f, 0.f, 0.f, 0.f};
  f32x4 acc[4];
  float den[4];
#pragma unroll
  for (int f = 0; f < 4; ++f) { acc[f] = zero; den[f] = 0.f; }

  const int mb = wv * (NN / 4);  // this wave's m-slice
  bf16x4 kf = *(const bf16x4*)(th + (size_t)(mb + lr) * DH + 4 * lg);
  bf16x4 vf = *(const bf16x4*)(vrow + mb + 4 * lg);
  for (int mt = 0; mt < NN / 64; ++mt) {  // 32 tiles of 16
    bf16x4 kf_n = kf, vf_n = vf;
    if (mt < NN / 64 - 1) {
      const int mn = mb + (mt + 1) * 16;
      kf_n = *(const bf16x4*)(th + (size_t)(mn + lr) * DH + 4 * lg);
      vf_n = *(const bf16x4*)(vrow + mn + 4 * lg);
    }
#pragma unroll
    for (int f = 0; f < 4; ++f) {
      f32x4 s = MFMA16(kf, qf[f], zero);  // S'[m,q] = S*log2e; lane: col q, rows m
      float p0 = EXP2F(s[0]), p1 = EXP2F(s[1]), p2 = EXP2F(s[2]), p3 = EXP2F(s[3]);
      den[f] += (p0 + p1) + (p2 + p3);
      bf16x4 pf;
      pf[0] = (short)f2bf(p0); pf[1] = (short)f2bf(p1);
      pf[2] = (short)f2bf(p2); pf[3] = (short)f2bf(p3);
      acc[f] = MFMA16(pf, vf, acc[f]);  // lane: col d=lr, rows q=16f+4lg+reg
    }
    kf = kf_n; vf = vf_n;
  }
  // intra-wave den reduce over lg groups -> every lane holds den for q=lr
#pragma unroll
  for (int f = 0; f < 4; ++f) {
    den[f] += __shfl_xor(den[f], 16);
    den[f] += __shfl_xor(den[f], 32);
  }
  // stash partials
#pragma unroll
  for (int f = 0; f < 4; ++f) {
#pragma unroll
    for (int reg = 0; reg < 4; ++reg) dnum[wv][f][4 * lg + reg][lr] = acc[f][reg];
    if (lane < 16) dden[wv][f][lane] = den[f];
  }
  __syncthreads();
  // combine 4 waves, write out: t -> (frag, qrow, 4 d's)
  const int t = threadIdx.x;
  const int f = t >> 6, r = (t >> 2) & 15, du = (t & 3) * 4;
  float4 n0v = *(const float4*)&dnum[0][f][r][du];
  float4 n1v = *(const float4*)&dnum[1][f][r][du];
  float4 n2v = *(const float4*)&dnum[2][f][r][du];
  float4 n3v = *(const float4*)&dnum[3][f][r][du];
  const float dsum = dden[0][f][r] + dden[1][f][r] + dden[2][f][r] + dden[3][f][r];
  const float inv = -1.f / dsum;
  float4 o;
  o.x = (n0v.x + n1v.x + n2v.x + n3v.x) * inv;
  o.y = (n0v.y + n1v.y + n2v.y + n3v.y) * inv;
  o.z = (n0v.z + n1v.z + n2v.z + n3v.z) * inv;
  o.w = (n0v.w + n1v.w + n2v.w + n3v.w) * inv;
  *(float4*)(out + ((size_t)b * NN + q0 + 16 * f + r) * LL + h * DH + du) = o;
}

extern "C" void kernel_launch(void* const* d_in, const int* in_sizes, int n_in,
                              void* d_out, int out_size, void* d_ws, size_t ws_size,
                              hipStream_t stream) {
  const float* c = (const float*)d_in[0];
  const float* state = (const float*)d_in[3];
  const float* E = (const float*)d_in[4];
  const float* Wp = (const float*)d_in[13];
  const float* bp = (const float*)d_in[14];
  float* out = (float*)d_out;

  unsigned short* A16 = (unsigned short*)d_ws;        // 2048*2048 bf16 = 8 MB
  unsigned short* cT16 = A16 + (size_t)NN * NN;       // 2 MB
  unsigned short* WpTh = cT16 + (size_t)BB * LL * NN; // 256 KB
  unsigned short* WpTl = WpTh + (size_t)LL * KT;      // 256 KB
  float* cg = (float*)(WpTl + (size_t)LL * KT);       // 4 MB
  float* ctb = cg + (size_t)BB * NN * LL;             // 4 MB
  unsigned short* th16 = (unsigned short*)(ctb + (size_t)BB * NN * LL);  // 2 MB
  unsigned short* thq16 = th16 + (size_t)HB * NN * DH;                   // 2 MB
  unsigned short* vt16 = thq16 + (size_t)HB * NN * DH;                   // 2 MB

  k_rowsoftmax<<<NN / 2, 256, 0, stream>>>(E, A16);
  k_prep_c<<<dim3(NN / 64, BB), 256, 0, stream>>>(c, cT16);
  k_prep_w<<<KT / 64, 256, 0, stream>>>(Wp, WpTh, WpTl);
  k_gemm1<<<dim3(NN / 64, BB), 256, 0, stream>>>(A16, cT16, cg);
  k_gcn2<<<dim3(NN / 64, BB), 256, 0, stream>>>(E, WpTh, WpTl, bp, c, cg, ctb);
  k_prep<<<dim3(HB, NN / 64), 256, 0, stream>>>(state, ctb, th16, thq16, vt16);
  k_attn3<<<dim3(HB, NN / 64), 256, 0, stream>>>(th16, thq16, vt16, out);
}

// Round 8
// 88.215 us; speedup vs baseline: 3.8361x; 1.4703x over previous
//
#include <hip/hip_runtime.h>
#include <hip/hip_bf16.h>

#define NN 2048
#define BB 8
#define LL 64
#define ADA 16
#define DH 16
#define HB 32
#define KT 2048  // GCN GEMM total K = ADA*2*LL

typedef __attribute__((ext_vector_type(4))) short bf16x4;
typedef __attribute__((ext_vector_type(4))) float f32x4;
typedef __attribute__((ext_vector_type(8))) unsigned short ushort8v;
typedef _Float16 half_t;
typedef __attribute__((ext_vector_type(4))) _Float16 halfx4;
typedef __attribute__((ext_vector_type(8))) _Float16 halfx8;

// __has_builtin(__builtin_amdgcn_mfma_*) is FALSE on the host pass of hipcc's
// dual compile -> guard with __HIP_DEVICE_COMPILE__, parse-only dummy on host.
#if defined(__HIP_DEVICE_COMPILE__)
#if __has_builtin(__builtin_amdgcn_mfma_f32_16x16x16bf16_1k)
#define MFMA16(a, b, c) __builtin_amdgcn_mfma_f32_16x16x16bf16_1k(a, b, c, 0, 0, 0)
#elif __has_builtin(__builtin_amdgcn_mfma_f32_16x16x16_bf16)
#define MFMA16(a, b, c) __builtin_amdgcn_mfma_f32_16x16x16_bf16(a, b, c, 0, 0, 0)
#else
#error "no 16x16x16 bf16 mfma builtin on device"
#endif
#if __has_builtin(__builtin_amdgcn_mfma_f32_16x16x16f16)
#define MFMA16H(a, b, c) __builtin_amdgcn_mfma_f32_16x16x16f16(a, b, c, 0, 0, 0)
#elif __has_builtin(__builtin_amdgcn_mfma_f32_16x16x16_f16)
#define MFMA16H(a, b, c) __builtin_amdgcn_mfma_f32_16x16x16_f16(a, b, c, 0, 0, 0)
#else
#error "no 16x16x16 f16 mfma builtin on device"
#endif
#if __has_builtin(__builtin_amdgcn_exp2f)
#define EXP2F(x) __builtin_amdgcn_exp2f(x)
#else
#define EXP2F(x) exp2f(x)
#endif
#else
#define MFMA16(a, b, c) (c)
#define MFMA16H(a, b, c) (c)
#define EXP2F(x) exp2f(x)
#endif

__device__ inline unsigned short f2bf(float x) {
  __hip_bfloat16 h = __float2bfloat16(x);
  return *reinterpret_cast<unsigned short*>(&h);
}
__device__ inline float tanh_fast(float v) {
  return 1.f - 2.f / (__expf(2.f * v) + 1.f);
}

// ---------------- K1: A16 = bf16(rowsoftmax(relu(E E^T))), 2 rows/block ----------------
__global__ __launch_bounds__(256) void k_rowsoftmax(const float* __restrict__ E,
                                                    unsigned short* __restrict__ A16) {
  __shared__ float row[2][NN];
  __shared__ float red[2][256];
  const int n = blockIdx.x * 2;
  const int t = threadIdx.x;
  float4 e0[4], e1[4];
  const float4* E0 = (const float4*)(E + (size_t)n * ADA);
  const float4* E1 = (const float4*)(E + (size_t)(n + 1) * ADA);
#pragma unroll
  for (int j = 0; j < 4; ++j) { e0[j] = E0[j]; e1[j] = E1[j]; }
  float l0 = 0.f, l1 = 0.f;
  for (int m = t; m < NN; m += 256) {
    const float4* Em = (const float4*)(E + (size_t)m * ADA);
    float s0 = 0.f, s1 = 0.f;
#pragma unroll
    for (int j = 0; j < 4; ++j) {
      float4 ev = Em[j];
      s0 = fmaf(e0[j].x, ev.x, fmaf(e0[j].y, ev.y, fmaf(e0[j].z, ev.z, fmaf(e0[j].w, ev.w, s0))));
      s1 = fmaf(e1[j].x, ev.x, fmaf(e1[j].y, ev.y, fmaf(e1[j].z, ev.z, fmaf(e1[j].w, ev.w, s1))));
    }
    float p0 = __expf(fmaxf(s0, 0.f) - 20.f);  // fixed shift; cancels in normalize
    float p1 = __expf(fmaxf(s1, 0.f) - 20.f);
    row[0][m] = p0; row[1][m] = p1;
    l0 += p0; l1 += p1;
  }
  red[0][t] = l0; red[1][t] = l1;
  __syncthreads();
  for (int off = 128; off > 0; off >>= 1) {
    if (t < off) { red[0][t] += red[0][t + off]; red[1][t] += red[1][t + off]; }
    __syncthreads();
  }
  const float i0 = 1.f / red[0][0], i1 = 1.f / red[1][0];
  for (int m = t; m < NN; m += 256) {
    A16[(size_t)n * NN + m] = f2bf(row[0][m] * i0);
    A16[(size_t)(n + 1) * NN + m] = f2bf(row[1][m] * i1);
  }
}

// ---------------- K2a: cT16[b][o][m] = bf16(c[b][m][o]) ----------------
__global__ __launch_bounds__(256) void k_prep_c(const float* __restrict__ c,
                                                unsigned short* __restrict__ cT16) {
  __shared__ float ld[64][68];
  const int m0 = blockIdx.x * 64;
  const int b = blockIdx.y;
  const int t = threadIdx.x;
  {
    const int r = t & 63, cq = t >> 6;
    const float* cp = c + ((size_t)b * NN + m0 + r) * LL + cq * 16;
#pragma unroll
    for (int u = 0; u < 4; ++u)
      *(float4*)&ld[r][cq * 16 + 4 * u] = *(const float4*)(cp + 4 * u);
  }
  __syncthreads();
  const int o = t & 63, mq = t >> 6;
  unsigned short outv[16];
#pragma unroll
  for (int v = 0; v < 16; ++v) outv[v] = f2bf(ld[mq * 16 + v][o]);
  unsigned short* op = cT16 + ((size_t)b * LL + o) * NN + m0 + mq * 16;
  *(ushort8v*)op = *(const ushort8v*)&outv[0];
  *(ushort8v*)(op + 8) = *(const ushort8v*)&outv[8];
}

// ---------------- K2b: WpT[o][ktot] = fp16(Wp[ktot][o]) ----------------
__global__ __launch_bounds__(256) void k_prep_w(const float* __restrict__ Wp,
                                                half_t* __restrict__ WpT) {
  __shared__ float ld[64][68];
  const int k0 = blockIdx.x * 64;
  const int t = threadIdx.x;
  {
    const int r = t & 63, cq = t >> 6;
    const float* wp = Wp + (size_t)(k0 + r) * LL + cq * 16;
#pragma unroll
    for (int u = 0; u < 4; ++u)
      *(float4*)&ld[r][cq * 16 + 4 * u] = *(const float4*)(wp + 4 * u);
  }
  __syncthreads();
  const int o = t & 63, kq = t >> 6;
  halfx8 h0, h1;
#pragma unroll
  for (int v = 0; v < 8; ++v) {
    h0[v] = (half_t)ld[kq * 16 + v][o];
    h1[v] = (half_t)ld[kq * 16 + 8 + v][o];
  }
  half_t* op = WpT + (size_t)o * KT + k0 + kq * 16;
  *(halfx8*)op = h0;
  *(halfx8*)(op + 8) = h1;
}

// ---------------- K3: cg[b] = A @ c[b], bf16 16x16x16 MFMA (validated), K-split x2 ----------------
__global__ __launch_bounds__(256) void k_gemm1(const unsigned short* __restrict__ A16,
                                               const unsigned short* __restrict__ cT16,
                                               float* __restrict__ cg0,
                                               float* __restrict__ cg1) {
  __shared__ unsigned short sA[64][72];
  __shared__ unsigned short sB[64][72];
  const int t = threadIdx.x;
  const int n0 = blockIdx.x * 64;
  const int b = blockIdx.y;
  const int kh = blockIdx.z;
  const int wv = t >> 6, lane = t & 63;
  const int lr = lane & 15, lg = lane >> 4;
  const unsigned short* cb = cT16 + (size_t)b * LL * NN;
  const int sr = t >> 2, sc = (t & 3) * 16;
  f32x4 acc[4];
#pragma unroll
  for (int ot = 0; ot < 4; ++ot) acc[ot] = (f32x4){0.f, 0.f, 0.f, 0.f};

  for (int k0 = kh * (NN / 2); k0 < (kh + 1) * (NN / 2); k0 += 64) {
    __syncthreads();
    {
      const unsigned short* ga = A16 + (size_t)(n0 + sr) * NN + k0 + sc;
      *(ushort8v*)&sA[sr][sc] = *(const ushort8v*)ga;
      *(ushort8v*)&sA[sr][sc + 8] = *(const ushort8v*)(ga + 8);
      const unsigned short* gb = cb + (size_t)sr * NN + k0 + sc;
      *(ushort8v*)&sB[sr][sc] = *(const ushort8v*)gb;
      *(ushort8v*)&sB[sr][sc + 8] = *(const ushort8v*)(gb + 8);
    }
    __syncthreads();
#pragma unroll
    for (int ks = 0; ks < 4; ++ks) {
      bf16x4 a = *(const bf16x4*)&sA[16 * wv + lr][ks * 16 + 4 * lg];
#pragma unroll
      for (int ot = 0; ot < 4; ++ot) {
        bf16x4 bq = *(const bf16x4*)&sB[ot * 16 + lr][ks * 16 + 4 * lg];
        acc[ot] = MFMA16(a, bq, acc[ot]);
      }
    }
  }
  float* outp = (kh ? cg1 : cg0) + ((size_t)b * NN + n0 + 16 * wv) * LL;
#pragma unroll
  for (int ot = 0; ot < 4; ++ot)
#pragma unroll
    for (int reg = 0; reg < 4; ++reg)
      outp[(size_t)(4 * lg + reg) * LL + ot * 16 + lr] = acc[ot][reg];
}

// ---------------- K4: ctp[dh] = sum_{d in half} E[n,d]*(xg @ Wp[d]) (+bias in dh0) ----------------
// E folded into A-operand (per-lane scalar). fp16 16x16x16 MFMA (validated layout family).
// NOTE R6/R7 bug: sW row width was 72 but cols go to 127 -> inter-row aliasing. Now [136].
__global__ __launch_bounds__(256) void k_gcn3(const float* __restrict__ E,
                                              const half_t* __restrict__ WpT,
                                              const float* __restrict__ bp,
                                              const float* __restrict__ c,
                                              const float* __restrict__ cg0,
                                              const float* __restrict__ cg1,
                                              float* __restrict__ ctp0,
                                              float* __restrict__ ctp1) {
  __shared__ half_t sW[64][136];  // 128 data cols + 8 pad (17.4 KB)
  __shared__ float sE[64][17];
  __shared__ float sbp[16][64];
  const int t = threadIdx.x;
  const int n0 = blockIdx.x * 64;
  const int b = blockIdx.y;
  const int dh = blockIdx.z;
  const int wv = t >> 6, lane = t & 63;
  const int lr = lane & 15, lg = lane >> 4;
  {
    const int r = t >> 2, dq = (t & 3) * 4;
    float4 ev = *(const float4*)(E + (size_t)(n0 + r) * ADA + dq);
    sE[r][dq + 0] = ev.x; sE[r][dq + 1] = ev.y;
    sE[r][dq + 2] = ev.z; sE[r][dq + 3] = ev.w;
    const int bi = t * 4;
    *(float4*)&sbp[bi >> 6][bi & 63] = *(const float4*)(bp + bi);
  }
  // x (c | cg0+cg1) into registers. A-frag row = lr, k = 4*lg+j per 16-k tile.
  float xr[8][4];
  {
    const size_t rbase = ((size_t)b * NN + n0 + 16 * wv + lr) * LL;
#pragma unroll
    for (int q = 0; q < 4; ++q) {
      float4 v = *(const float4*)(c + rbase + q * 16 + 4 * lg);
      xr[q][0] = v.x; xr[q][1] = v.y; xr[q][2] = v.z; xr[q][3] = v.w;
    }
#pragma unroll
    for (int q = 0; q < 4; ++q) {
      float4 a = *(const float4*)(cg0 + rbase + q * 16 + 4 * lg);
      float4 b2 = *(const float4*)(cg1 + rbase + q * 16 + 4 * lg);
      xr[4 + q][0] = a.x + b2.x; xr[4 + q][1] = a.y + b2.y;
      xr[4 + q][2] = a.z + b2.z; xr[4 + q][3] = a.w + b2.w;
    }
  }
  __syncthreads();
  // acc init: bias (dh==0) or zero; D rows = 16wv + 4lg + reg, cols = ot*16+lr
  f32x4 acc[4];
  if (dh == 0) {
#pragma unroll
    for (int ot = 0; ot < 4; ++ot) {
      f32x4 s = (f32x4){0.f, 0.f, 0.f, 0.f};
#pragma unroll
      for (int d = 0; d < ADA; ++d) {
        const float bpv = sbp[d][ot * 16 + lr];
#pragma unroll
        for (int reg = 0; reg < 4; ++reg)
          s[reg] = fmaf(sE[16 * wv + 4 * lg + reg][d], bpv, s[reg]);
      }
      acc[ot] = s;
    }
  } else {
#pragma unroll
    for (int ot = 0; ot < 4; ++ot) acc[ot] = (f32x4){0.f, 0.f, 0.f, 0.f};
  }
  // W staging: thread covers o-row so, 8-half chunks (sq+4u)
  const int so = t >> 2, sq = t & 3;
  halfx8 wreg[4];
  {
    const half_t* p = WpT + (size_t)so * KT + (size_t)(dh * 8) * 128;
#pragma unroll
    for (int u = 0; u < 4; ++u) wreg[u] = *(const halfx8*)(p + (sq + 4 * u) * 8);
  }
  for (int dd = 0; dd < 8; ++dd) {
    __syncthreads();  // previous iteration's MFMAs done with sW
#pragma unroll
    for (int u = 0; u < 4; ++u) *(halfx8*)&sW[so][(sq + 4 * u) * 8] = wreg[u];
    __syncthreads();  // sW ready
    if (dd < 7) {
      const half_t* p = WpT + (size_t)so * KT + (size_t)(dh * 8 + dd + 1) * 128;
#pragma unroll
      for (int u = 0; u < 4; ++u) wreg[u] = *(const halfx8*)(p + (sq + 4 * u) * 8);
    }
    const float e = sE[16 * wv + lr][dh * 8 + dd];
    halfx4 af[8];
#pragma unroll
    for (int kt = 0; kt < 8; ++kt)
#pragma unroll
      for (int j = 0; j < 4; ++j) af[kt][j] = (half_t)(e * xr[kt][j]);
#pragma unroll
    for (int kt = 0; kt < 8; ++kt) {
#pragma unroll
      for (int ot = 0; ot < 4; ++ot) {
        halfx4 bq = *(const halfx4*)&sW[ot * 16 + lr][kt * 16 + 4 * lg];
        acc[ot] = MFMA16H(af[kt], bq, acc[ot]);
      }
    }
  }
  float* op = (dh ? ctp1 : ctp0) + ((size_t)b * NN + n0 + 16 * wv) * LL;
#pragma unroll
  for (int ot = 0; ot < 4; ++ot)
#pragma unroll
    for (int reg = 0; reg < 4; ++reg)
      op[(size_t)(4 * lg + reg) * LL + ot * 16 + lr] = acc[ot][reg];
}

// ---------------- K5: prep — tanh(ctp0+ctp1) -> vt16; th16 (K), thq16 (Q scaled) ----------------
__global__ __launch_bounds__(256) void k_prep(const float* __restrict__ state,
                                              const float* __restrict__ ctp0,
                                              const float* __restrict__ ctp1,
                                              unsigned short* __restrict__ th16,
                                              unsigned short* __restrict__ thq16,
                                              unsigned short* __restrict__ vt16) {
  __shared__ unsigned short vt[16][68];
  const int hb = blockIdx.x;
  const int h = hb >> 3, b = hb & 7;
  const int n0 = blockIdx.y * 64;
  const int t = threadIdx.x;
  const int r = t >> 2, dq = t & 3;
  const float QS = 0.25f * 1.4426950408889634f;  // fold score scale + log2(e) into Q
  const float* sp = state + ((size_t)b * NN + n0 + r) * LL + h * DH + 4 * dq;
  float4 sv = *(const float4*)sp;
  ushort4 tk = make_ushort4(f2bf(sv.x), f2bf(sv.y), f2bf(sv.z), f2bf(sv.w));
  *(ushort4*)(th16 + ((size_t)hb * NN + n0 + r) * DH + 4 * dq) = tk;
  ushort4 tq = make_ushort4(f2bf(QS * sv.x), f2bf(QS * sv.y),
                            f2bf(QS * sv.z), f2bf(QS * sv.w));
  *(ushort4*)(thq16 + ((size_t)hb * NN + n0 + r) * DH + 4 * dq) = tq;
  const size_t cidx = ((size_t)b * NN + n0 + r) * LL + h * DH + 4 * dq;
  float4 p0 = *(const float4*)(ctp0 + cidx);
  float4 p1 = *(const float4*)(ctp1 + cidx);
  vt[4 * dq + 0][r] = f2bf(tanh_fast(p0.x + p1.x));
  vt[4 * dq + 1][r] = f2bf(tanh_fast(p0.y + p1.y));
  vt[4 * dq + 2][r] = f2bf(tanh_fast(p0.z + p1.z));
  vt[4 * dq + 3][r] = f2bf(tanh_fast(p0.w + p1.w));
  __syncthreads();
  const int d = t >> 4, mq = t & 15;
  ushort4 o = make_ushort4(vt[d][4 * mq + 0], vt[d][4 * mq + 1],
                           vt[d][4 * mq + 2], vt[d][4 * mq + 3]);
  *(ushort4*)(vt16 + ((size_t)hb * DH + d) * NN + n0 + 4 * mq) = o;
}

// ---------------- K6: MFMA attention — 64 q/wave (4 frags), split-m across 4 waves ----------------
__global__ __launch_bounds__(256) void k_attn3(const unsigned short* __restrict__ th16,
                                               const unsigned short* __restrict__ thq16,
                                               const unsigned short* __restrict__ vt16,
                                               float* __restrict__ out) {
  __shared__ float dnum[4][4][16][16];  // [wave][frag][qrow][d]
  __shared__ float dden[4][4][16];      // [wave][frag][q]
  const int hb = blockIdx.x;
  const int h = hb >> 3, b = hb & 7;
  const int wv = threadIdx.x >> 6, lane = threadIdx.x & 63;
  const int q0 = blockIdx.y * 64;
  const int lr = lane & 15, lg = lane >> 4;
  const unsigned short* th = th16 + (size_t)hb * NN * DH;
  const unsigned short* thq = thq16 + (size_t)hb * NN * DH;
  const unsigned short* vrow = vt16 + ((size_t)hb * DH + lr) * NN;  // V^T row d=lr
  bf16x4 qf[4];
#pragma unroll
  for (int f = 0; f < 4; ++f)
    qf[f] = *(const bf16x4*)(thq + (size_t)(q0 + 16 * f + lr) * DH + 4 * lg);
  const f32x4 zero = {0.f, 0.f, 0.f, 0.f};
  f32x4 acc[4];
  float den[4];
#pragma unroll
  for (int f = 0; f < 4; ++f) { acc[f] = zero; den[f] = 0.f; }

  const int mb = wv * (NN / 4);  // this wave's m-slice
  bf16x4 kf = *(const bf16x4*)(th + (size_t)(mb + lr) * DH + 4 * lg);
  bf16x4 vf = *(const bf16x4*)(vrow + mb + 4 * lg);
  for (int mt = 0; mt < NN / 64; ++mt) {  // 32 tiles of 16
    bf16x4 kf_n = kf, vf_n = vf;
    if (mt < NN / 64 - 1) {
      const int mn = mb + (mt + 1) * 16;
      kf_n = *(const bf16x4*)(th + (size_t)(mn + lr) * DH + 4 * lg);
      vf_n = *(const bf16x4*)(vrow + mn + 4 * lg);
    }
#pragma unroll
    for (int f = 0; f < 4; ++f) {
      f32x4 s = MFMA16(kf, qf[f], zero);  // lane: col q, rows m
      float p0 = EXP2F(s[0]), p1 = EXP2F(s[1]), p2 = EXP2F(s[2]), p3 = EXP2F(s[3]);
      den[f] += (p0 + p1) + (p2 + p3);
      bf16x4 pf;
      pf[0] = (short)f2bf(p0); pf[1] = (short)f2bf(p1);
      pf[2] = (short)f2bf(p2); pf[3] = (short)f2bf(p3);
      acc[f] = MFMA16(pf, vf, acc[f]);  // lane: col d=lr, rows q=16f+4lg+reg
    }
    kf = kf_n; vf = vf_n;
  }
#pragma unroll
  for (int f = 0; f < 4; ++f) {
    den[f] += __shfl_xor(den[f], 16);
    den[f] += __shfl_xor(den[f], 32);
  }
#pragma unroll
  for (int f = 0; f < 4; ++f) {
#pragma unroll
    for (int reg = 0; reg < 4; ++reg) dnum[wv][f][4 * lg + reg][lr] = acc[f][reg];
    if (lane < 16) dden[wv][f][lane] = den[f];
  }
  __syncthreads();
  const int t = threadIdx.x;
  const int f = t >> 6, r = (t >> 2) & 15, du = (t & 3) * 4;
  float4 n0v = *(const float4*)&dnum[0][f][r][du];
  float4 n1v = *(const float4*)&dnum[1][f][r][du];
  float4 n2v = *(const float4*)&dnum[2][f][r][du];
  float4 n3v = *(const float4*)&dnum[3][f][r][du];
  const float dsum = dden[0][f][r] + dden[1][f][r] + dden[2][f][r] + dden[3][f][r];
  const float inv = -1.f / dsum;
  float4 o;
  o.x = (n0v.x + n1v.x + n2v.x + n3v.x) * inv;
  o.y = (n0v.y + n1v.y + n2v.y + n3v.y) * inv;
  o.z = (n0v.z + n1v.z + n2v.z + n3v.z) * inv;
  o.w = (n0v.w + n1v.w + n2v.w + n3v.w) * inv;
  *(float4*)(out + ((size_t)b * NN + q0 + 16 * f + r) * LL + h * DH + du) = o;
}

extern "C" void kernel_launch(void* const* d_in, const int* in_sizes, int n_in,
                              void* d_out, int out_size, void* d_ws, size_t ws_size,
                              hipStream_t stream) {
  const float* c = (const float*)d_in[0];
  const float* state = (const float*)d_in[3];
  const float* E = (const float*)d_in[4];
  const float* Wp = (const float*)d_in[13];
  const float* bp = (const float*)d_in[14];
  float* out = (float*)d_out;

  unsigned short* A16 = (unsigned short*)d_ws;        // 2048*2048 bf16 = 8 MB
  unsigned short* cT16 = A16 + (size_t)NN * NN;       // 2 MB
  half_t* WpT = (half_t*)(cT16 + (size_t)BB * LL * NN);  // 256 KB
  float* cg0 = (float*)(WpT + (size_t)LL * KT);       // 4 MB
  float* cg1 = cg0 + (size_t)BB * NN * LL;            // 4 MB
  float* ctp0 = cg1 + (size_t)BB * NN * LL;           // 4 MB
  float* ctp1 = ctp0 + (size_t)BB * NN * LL;          // 4 MB
  unsigned short* th16 = (unsigned short*)(ctp1 + (size_t)BB * NN * LL);  // 2 MB
  unsigned short* thq16 = th16 + (size_t)HB * NN * DH;                    // 2 MB
  unsigned short* vt16 = thq16 + (size_t)HB * NN * DH;                    // 2 MB

  k_rowsoftmax<<<NN / 2, 256, 0, stream>>>(E, A16);
  k_prep_c<<<dim3(NN / 64, BB), 256, 0, stream>>>(c, cT16);
  k_prep_w<<<KT / 64, 256, 0, stream>>>(Wp, WpT);
  k_gemm1<<<dim3(NN / 64, BB, 2), 256, 0, stream>>>(A16, cT16, cg0, cg1);
  k_gcn3<<<dim3(NN / 64, BB, 2), 256, 0, stream>>>(E, WpT, bp, c, cg0, cg1, ctp0, ctp1);
  k_prep<<<dim3(HB, NN / 64), 256, 0, stream>>>(state, ctp0, ctp1, th16, thq16, vt16);
  k_attn3<<<dim3(HB, NN / 64), 256, 0, stream>>>(th16, thq16, vt16, out);
}

// Round 9
// 82.120 us; speedup vs baseline: 4.1208x; 1.0742x over previous
//
#include <hip/hip_runtime.h>
#include <hip/hip_bf16.h>

#define NN 2048
#define BB 8
#define LL 64
#define ADA 16
#define DH 16
#define HB 32
#define KT 2048  // GCN GEMM total K = ADA*2*LL

typedef __attribute__((ext_vector_type(4))) short bf16x4;
typedef __attribute__((ext_vector_type(4))) float f32x4;
typedef __attribute__((ext_vector_type(8))) unsigned short ushort8v;
typedef _Float16 half_t;
typedef __attribute__((ext_vector_type(4))) _Float16 halfx4;
typedef __attribute__((ext_vector_type(8))) _Float16 halfx8;

// __has_builtin(__builtin_amdgcn_mfma_*) is FALSE on the host pass of hipcc's
// dual compile -> guard with __HIP_DEVICE_COMPILE__, parse-only dummy on host.
#if defined(__HIP_DEVICE_COMPILE__)
#if __has_builtin(__builtin_amdgcn_mfma_f32_16x16x16bf16_1k)
#define MFMA16(a, b, c) __builtin_amdgcn_mfma_f32_16x16x16bf16_1k(a, b, c, 0, 0, 0)
#elif __has_builtin(__builtin_amdgcn_mfma_f32_16x16x16_bf16)
#define MFMA16(a, b, c) __builtin_amdgcn_mfma_f32_16x16x16_bf16(a, b, c, 0, 0, 0)
#else
#error "no 16x16x16 bf16 mfma builtin on device"
#endif
#if __has_builtin(__builtin_amdgcn_mfma_f32_16x16x16f16)
#define MFMA16H(a, b, c) __builtin_amdgcn_mfma_f32_16x16x16f16(a, b, c, 0, 0, 0)
#elif __has_builtin(__builtin_amdgcn_mfma_f32_16x16x16_f16)
#define MFMA16H(a, b, c) __builtin_amdgcn_mfma_f32_16x16x16_f16(a, b, c, 0, 0, 0)
#else
#error "no 16x16x16 f16 mfma builtin on device"
#endif
#if __has_builtin(__builtin_amdgcn_exp2f)
#define EXP2F(x) __builtin_amdgcn_exp2f(x)
#else
#define EXP2F(x) exp2f(x)
#endif
#else
#define MFMA16(a, b, c) (c)
#define MFMA16H(a, b, c) (c)
#define EXP2F(x) exp2f(x)
#endif

__device__ inline unsigned short f2bf(float x) {
  __hip_bfloat16 h = __float2bfloat16(x);
  return *reinterpret_cast<unsigned short*>(&h);
}
__device__ inline float tanh_fast(float v) {
  return 1.f - 2.f / (__expf(2.f * v) + 1.f);
}

// ---------------- K1: A16 = bf16(rowsoftmax(relu(E E^T))), 2 rows/block ----------------
__global__ __launch_bounds__(256) void k_rowsoftmax(const float* __restrict__ E,
                                                    unsigned short* __restrict__ A16) {
  __shared__ float row[2][NN];
  __shared__ float red[2][256];
  const int n = blockIdx.x * 2;
  const int t = threadIdx.x;
  float4 e0[4], e1[4];
  const float4* E0 = (const float4*)(E + (size_t)n * ADA);
  const float4* E1 = (const float4*)(E + (size_t)(n + 1) * ADA);
#pragma unroll
  for (int j = 0; j < 4; ++j) { e0[j] = E0[j]; e1[j] = E1[j]; }
  float l0 = 0.f, l1 = 0.f;
  for (int m = t; m < NN; m += 256) {
    const float4* Em = (const float4*)(E + (size_t)m * ADA);
    float s0 = 0.f, s1 = 0.f;
#pragma unroll
    for (int j = 0; j < 4; ++j) {
      float4 ev = Em[j];
      s0 = fmaf(e0[j].x, ev.x, fmaf(e0[j].y, ev.y, fmaf(e0[j].z, ev.z, fmaf(e0[j].w, ev.w, s0))));
      s1 = fmaf(e1[j].x, ev.x, fmaf(e1[j].y, ev.y, fmaf(e1[j].z, ev.z, fmaf(e1[j].w, ev.w, s1))));
    }
    float p0 = __expf(fmaxf(s0, 0.f) - 20.f);  // fixed shift; cancels in normalize
    float p1 = __expf(fmaxf(s1, 0.f) - 20.f);
    row[0][m] = p0; row[1][m] = p1;
    l0 += p0; l1 += p1;
  }
  red[0][t] = l0; red[1][t] = l1;
  __syncthreads();
  for (int off = 128; off > 0; off >>= 1) {
    if (t < off) { red[0][t] += red[0][t + off]; red[1][t] += red[1][t + off]; }
    __syncthreads();
  }
  const float i0 = 1.f / red[0][0], i1 = 1.f / red[1][0];
  for (int m = t; m < NN; m += 256) {
    A16[(size_t)n * NN + m] = f2bf(row[0][m] * i0);
    A16[(size_t)(n + 1) * NN + m] = f2bf(row[1][m] * i1);
  }
}

// ---------------- K2a: cT16[b][o][m] = bf16(c[b][m][o]) ----------------
__global__ __launch_bounds__(256) void k_prep_c(const float* __restrict__ c,
                                                unsigned short* __restrict__ cT16) {
  __shared__ float ld[64][68];
  const int m0 = blockIdx.x * 64;
  const int b = blockIdx.y;
  const int t = threadIdx.x;
  {
    const int r = t & 63, cq = t >> 6;
    const float* cp = c + ((size_t)b * NN + m0 + r) * LL + cq * 16;
#pragma unroll
    for (int u = 0; u < 4; ++u)
      *(float4*)&ld[r][cq * 16 + 4 * u] = *(const float4*)(cp + 4 * u);
  }
  __syncthreads();
  const int o = t & 63, mq = t >> 6;
  unsigned short outv[16];
#pragma unroll
  for (int v = 0; v < 16; ++v) outv[v] = f2bf(ld[mq * 16 + v][o]);
  unsigned short* op = cT16 + ((size_t)b * LL + o) * NN + m0 + mq * 16;
  *(ushort8v*)op = *(const ushort8v*)&outv[0];
  *(ushort8v*)(op + 8) = *(const ushort8v*)&outv[8];
}

// ---------------- K2b: WpT[o][ktot] = fp16(Wp[ktot][o]) ----------------
__global__ __launch_bounds__(256) void k_prep_w(const float* __restrict__ Wp,
                                                half_t* __restrict__ WpT) {
  __shared__ float ld[64][68];
  const int k0 = blockIdx.x * 64;
  const int t = threadIdx.x;
  {
    const int r = t & 63, cq = t >> 6;
    const float* wp = Wp + (size_t)(k0 + r) * LL + cq * 16;
#pragma unroll
    for (int u = 0; u < 4; ++u)
      *(float4*)&ld[r][cq * 16 + 4 * u] = *(const float4*)(wp + 4 * u);
  }
  __syncthreads();
  const int o = t & 63, kq = t >> 6;
  halfx8 h0, h1;
#pragma unroll
  for (int v = 0; v < 8; ++v) {
    h0[v] = (half_t)ld[kq * 16 + v][o];
    h1[v] = (half_t)ld[kq * 16 + 8 + v][o];
  }
  half_t* op = WpT + (size_t)o * KT + k0 + kq * 16;
  *(halfx8*)op = h0;
  *(halfx8*)(op + 8) = h1;
}

// ---------------- K3: cg[b] = A @ c[b], bf16 16x16x16 MFMA (validated), K-split x2 ----------------
__global__ __launch_bounds__(256) void k_gemm1(const unsigned short* __restrict__ A16,
                                               const unsigned short* __restrict__ cT16,
                                               float* __restrict__ cg0,
                                               float* __restrict__ cg1) {
  __shared__ unsigned short sA[64][72];
  __shared__ unsigned short sB[64][72];
  const int t = threadIdx.x;
  const int n0 = blockIdx.x * 64;
  const int b = blockIdx.y;
  const int kh = blockIdx.z;
  const int wv = t >> 6, lane = t & 63;
  const int lr = lane & 15, lg = lane >> 4;
  const unsigned short* cb = cT16 + (size_t)b * LL * NN;
  const int sr = t >> 2, sc = (t & 3) * 16;
  f32x4 acc[4];
#pragma unroll
  for (int ot = 0; ot < 4; ++ot) acc[ot] = (f32x4){0.f, 0.f, 0.f, 0.f};

  for (int k0 = kh * (NN / 2); k0 < (kh + 1) * (NN / 2); k0 += 64) {
    __syncthreads();
    {
      const unsigned short* ga = A16 + (size_t)(n0 + sr) * NN + k0 + sc;
      *(ushort8v*)&sA[sr][sc] = *(const ushort8v*)ga;
      *(ushort8v*)&sA[sr][sc + 8] = *(const ushort8v*)(ga + 8);
      const unsigned short* gb = cb + (size_t)sr * NN + k0 + sc;
      *(ushort8v*)&sB[sr][sc] = *(const ushort8v*)gb;
      *(ushort8v*)&sB[sr][sc + 8] = *(const ushort8v*)(gb + 8);
    }
    __syncthreads();
#pragma unroll
    for (int ks = 0; ks < 4; ++ks) {
      bf16x4 a = *(const bf16x4*)&sA[16 * wv + lr][ks * 16 + 4 * lg];
#pragma unroll
      for (int ot = 0; ot < 4; ++ot) {
        bf16x4 bq = *(const bf16x4*)&sB[ot * 16 + lr][ks * 16 + 4 * lg];
        acc[ot] = MFMA16(a, bq, acc[ot]);
      }
    }
  }
  float* outp = (kh ? cg1 : cg0) + ((size_t)b * NN + n0 + 16 * wv) * LL;
#pragma unroll
  for (int ot = 0; ot < 4; ++ot)
#pragma unroll
    for (int reg = 0; reg < 4; ++reg)
      outp[(size_t)(4 * lg + reg) * LL + ot * 16 + lr] = acc[ot][reg];
}

// ---------------- K4: ctp[dh] = sum_{d in half} E[n,d]*(xg @ Wp[d]) (+bias in dh0) ----------------
// E folded into A-operand (per-lane scalar). fp16 16x16x16 MFMA. sW width 136 (R8 fix).
__global__ __launch_bounds__(256) void k_gcn3(const float* __restrict__ E,
                                              const half_t* __restrict__ WpT,
                                              const float* __restrict__ bp,
                                              const float* __restrict__ c,
                                              const float* __restrict__ cg0,
                                              const float* __restrict__ cg1,
                                              float* __restrict__ ctp0,
                                              float* __restrict__ ctp1) {
  __shared__ half_t sW[64][136];  // 128 data cols + 8 pad (17.4 KB)
  __shared__ float sE[64][17];
  __shared__ float sbp[16][64];
  const int t = threadIdx.x;
  const int n0 = blockIdx.x * 64;
  const int b = blockIdx.y;
  const int dh = blockIdx.z;
  const int wv = t >> 6, lane = t & 63;
  const int lr = lane & 15, lg = lane >> 4;
  {
    const int r = t >> 2, dq = (t & 3) * 4;
    float4 ev = *(const float4*)(E + (size_t)(n0 + r) * ADA + dq);
    sE[r][dq + 0] = ev.x; sE[r][dq + 1] = ev.y;
    sE[r][dq + 2] = ev.z; sE[r][dq + 3] = ev.w;
    const int bi = t * 4;
    *(float4*)&sbp[bi >> 6][bi & 63] = *(const float4*)(bp + bi);
  }
  // x (c | cg0+cg1) into registers. A-frag row = lr, k = 4*lg+j per 16-k tile.
  float xr[8][4];
  {
    const size_t rbase = ((size_t)b * NN + n0 + 16 * wv + lr) * LL;
#pragma unroll
    for (int q = 0; q < 4; ++q) {
      float4 v = *(const float4*)(c + rbase + q * 16 + 4 * lg);
      xr[q][0] = v.x; xr[q][1] = v.y; xr[q][2] = v.z; xr[q][3] = v.w;
    }
#pragma unroll
    for (int q = 0; q < 4; ++q) {
      float4 a = *(const float4*)(cg0 + rbase + q * 16 + 4 * lg);
      float4 b2 = *(const float4*)(cg1 + rbase + q * 16 + 4 * lg);
      xr[4 + q][0] = a.x + b2.x; xr[4 + q][1] = a.y + b2.y;
      xr[4 + q][2] = a.z + b2.z; xr[4 + q][3] = a.w + b2.w;
    }
  }
  __syncthreads();
  // acc init: bias (dh==0) or zero; D rows = 16wv + 4lg + reg, cols = ot*16+lr
  f32x4 acc[4];
  if (dh == 0) {
#pragma unroll
    for (int ot = 0; ot < 4; ++ot) {
      f32x4 s = (f32x4){0.f, 0.f, 0.f, 0.f};
#pragma unroll
      for (int d = 0; d < ADA; ++d) {
        const float bpv = sbp[d][ot * 16 + lr];
#pragma unroll
        for (int reg = 0; reg < 4; ++reg)
          s[reg] = fmaf(sE[16 * wv + 4 * lg + reg][d], bpv, s[reg]);
      }
      acc[ot] = s;
    }
  } else {
#pragma unroll
    for (int ot = 0; ot < 4; ++ot) acc[ot] = (f32x4){0.f, 0.f, 0.f, 0.f};
  }
  // W staging: thread covers o-row so, 8-half chunks (sq+4u)
  const int so = t >> 2, sq = t & 3;
  halfx8 wreg[4];
  {
    const half_t* p = WpT + (size_t)so * KT + (size_t)(dh * 8) * 128;
#pragma unroll
    for (int u = 0; u < 4; ++u) wreg[u] = *(const halfx8*)(p + (sq + 4 * u) * 8);
  }
  for (int dd = 0; dd < 8; ++dd) {
    __syncthreads();  // previous iteration's MFMAs done with sW
#pragma unroll
    for (int u = 0; u < 4; ++u) *(halfx8*)&sW[so][(sq + 4 * u) * 8] = wreg[u];
    __syncthreads();  // sW ready
    if (dd < 7) {
      const half_t* p = WpT + (size_t)so * KT + (size_t)(dh * 8 + dd + 1) * 128;
#pragma unroll
      for (int u = 0; u < 4; ++u) wreg[u] = *(const halfx8*)(p + (sq + 4 * u) * 8);
    }
    const float e = sE[16 * wv + lr][dh * 8 + dd];
    halfx4 af[8];
#pragma unroll
    for (int kt = 0; kt < 8; ++kt)
#pragma unroll
      for (int j = 0; j < 4; ++j) af[kt][j] = (half_t)(e * xr[kt][j]);
#pragma unroll
    for (int kt = 0; kt < 8; ++kt) {
#pragma unroll
      for (int ot = 0; ot < 4; ++ot) {
        halfx4 bq = *(const halfx4*)&sW[ot * 16 + lr][kt * 16 + 4 * lg];
        acc[ot] = MFMA16H(af[kt], bq, acc[ot]);
      }
    }
  }
  float* op = (dh ? ctp1 : ctp0) + ((size_t)b * NN + n0 + 16 * wv) * LL;
#pragma unroll
  for (int ot = 0; ot < 4; ++ot)
#pragma unroll
    for (int reg = 0; reg < 4; ++reg)
      op[(size_t)(4 * lg + reg) * LL + ot * 16 + lr] = acc[ot][reg];
}

// ---------------- K5: prep — tanh(ctp0+ctp1) -> vt16; th16 (K), thq16 (Q scaled) ----------------
__global__ __launch_bounds__(256) void k_prep(const float* __restrict__ state,
                                              const float* __restrict__ ctp0,
                                              const float* __restrict__ ctp1,
                                              unsigned short* __restrict__ th16,
                                              unsigned short* __restrict__ thq16,
                                              unsigned short* __restrict__ vt16) {
  __shared__ unsigned short vt[16][68];
  const int hb = blockIdx.x;
  const int h = hb >> 3, b = hb & 7;
  const int n0 = blockIdx.y * 64;
  const int t = threadIdx.x;
  const int r = t >> 2, dq = t & 3;
  const float QS = 0.25f * 1.4426950408889634f;  // fold score scale + log2(e) into Q
  const float* sp = state + ((size_t)b * NN + n0 + r) * LL + h * DH + 4 * dq;
  float4 sv = *(const float4*)sp;
  ushort4 tk = make_ushort4(f2bf(sv.x), f2bf(sv.y), f2bf(sv.z), f2bf(sv.w));
  *(ushort4*)(th16 + ((size_t)hb * NN + n0 + r) * DH + 4 * dq) = tk;
  ushort4 tq = make_ushort4(f2bf(QS * sv.x), f2bf(QS * sv.y),
                            f2bf(QS * sv.z), f2bf(QS * sv.w));
  *(ushort4*)(thq16 + ((size_t)hb * NN + n0 + r) * DH + 4 * dq) = tq;
  const size_t cidx = ((size_t)b * NN + n0 + r) * LL + h * DH + 4 * dq;
  float4 p0 = *(const float4*)(ctp0 + cidx);
  float4 p1 = *(const float4*)(ctp1 + cidx);
  vt[4 * dq + 0][r] = f2bf(tanh_fast(p0.x + p1.x));
  vt[4 * dq + 1][r] = f2bf(tanh_fast(p0.y + p1.y));
  vt[4 * dq + 2][r] = f2bf(tanh_fast(p0.z + p1.z));
  vt[4 * dq + 3][r] = f2bf(tanh_fast(p0.w + p1.w));
  __syncthreads();
  const int d = t >> 4, mq = t & 15;
  ushort4 o = make_ushort4(vt[d][4 * mq + 0], vt[d][4 * mq + 1],
                           vt[d][4 * mq + 2], vt[d][4 * mq + 3]);
  *(ushort4*)(vt16 + ((size_t)hb * DH + d) * NN + n0 + 4 * mq) = o;
}

// ---------------- K6: MFMA attention — 8 waves/block (512 thr), m split 8-way ----------------
__global__ __launch_bounds__(512, 8) void k_attn4(const unsigned short* __restrict__ th16,
                                                  const unsigned short* __restrict__ thq16,
                                                  const unsigned short* __restrict__ vt16,
                                                  float* __restrict__ out) {
  __shared__ float dnum[8][4][16][16];  // [wave][frag][qrow][d]  32 KB
  __shared__ float dden[8][4][16];      // [wave][frag][q]        2 KB
  const int hb = blockIdx.x;
  const int h = hb >> 3, b = hb & 7;
  const int wv = threadIdx.x >> 6, lane = threadIdx.x & 63;
  const int q0 = blockIdx.y * 64;
  const int lr = lane & 15, lg = lane >> 4;
  const unsigned short* th = th16 + (size_t)hb * NN * DH;
  const unsigned short* thq = thq16 + (size_t)hb * NN * DH;
  const unsigned short* vrow = vt16 + ((size_t)hb * DH + lr) * NN;  // V^T row d=lr
  bf16x4 qf[4];
#pragma unroll
  for (int f = 0; f < 4; ++f)
    qf[f] = *(const bf16x4*)(thq + (size_t)(q0 + 16 * f + lr) * DH + 4 * lg);
  const f32x4 zero = {0.f, 0.f, 0.f, 0.f};
  f32x4 acc[4];
  float den[4];
#pragma unroll
  for (int f = 0; f < 4; ++f) { acc[f] = zero; den[f] = 0.f; }

  const int mb = wv * (NN / 8);  // this wave's 256-row m-slice
  bf16x4 kf = *(const bf16x4*)(th + (size_t)(mb + lr) * DH + 4 * lg);
  bf16x4 vf = *(const bf16x4*)(vrow + mb + 4 * lg);
  for (int mt = 0; mt < NN / 128; ++mt) {  // 16 tiles of 16
    bf16x4 kf_n = kf, vf_n = vf;
    if (mt < NN / 128 - 1) {
      const int mn = mb + (mt + 1) * 16;
      kf_n = *(const bf16x4*)(th + (size_t)(mn + lr) * DH + 4 * lg);
      vf_n = *(const bf16x4*)(vrow + mn + 4 * lg);
    }
#pragma unroll
    for (int f = 0; f < 4; ++f) {
      f32x4 s = MFMA16(kf, qf[f], zero);  // lane: col q, rows m
      float p0 = EXP2F(s[0]), p1 = EXP2F(s[1]), p2 = EXP2F(s[2]), p3 = EXP2F(s[3]);
      den[f] += (p0 + p1) + (p2 + p3);
      bf16x4 pf;
      pf[0] = (short)f2bf(p0); pf[1] = (short)f2bf(p1);
      pf[2] = (short)f2bf(p2); pf[3] = (short)f2bf(p3);
      acc[f] = MFMA16(pf, vf, acc[f]);  // lane: col d=lr, rows q=16f+4lg+reg
    }
    kf = kf_n; vf = vf_n;
  }
#pragma unroll
  for (int f = 0; f < 4; ++f) {
    den[f] += __shfl_xor(den[f], 16);
    den[f] += __shfl_xor(den[f], 32);
  }
#pragma unroll
  for (int f = 0; f < 4; ++f) {
#pragma unroll
    for (int reg = 0; reg < 4; ++reg) dnum[wv][f][4 * lg + reg][lr] = acc[f][reg];
    if (lane < 16) dden[wv][f][lane] = den[f];
  }
  __syncthreads();
  // combine 8 wave-partials; 512 threads -> (frag, qrow, d-pair)
  const int t = threadIdx.x;
  const int f = t >> 7, rem = t & 127;
  const int r = rem >> 3, du = (rem & 7) * 2;
  float n0s = 0.f, n1s = 0.f, ds = 0.f;
#pragma unroll
  for (int w = 0; w < 8; ++w) {
    n0s += dnum[w][f][r][du];
    n1s += dnum[w][f][r][du + 1];
    ds += dden[w][f][r];
  }
  const float inv = -1.f / ds;
  float2 o = make_float2(n0s * inv, n1s * inv);
  *(float2*)(out + ((size_t)b * NN + q0 + 16 * f + r) * LL + h * DH + du) = o;
}

extern "C" void kernel_launch(void* const* d_in, const int* in_sizes, int n_in,
                              void* d_out, int out_size, void* d_ws, size_t ws_size,
                              hipStream_t stream) {
  const float* c = (const float*)d_in[0];
  const float* state = (const float*)d_in[3];
  const float* E = (const float*)d_in[4];
  const float* Wp = (const float*)d_in[13];
  const float* bp = (const float*)d_in[14];
  float* out = (float*)d_out;

  unsigned short* A16 = (unsigned short*)d_ws;        // 2048*2048 bf16 = 8 MB
  unsigned short* cT16 = A16 + (size_t)NN * NN;       // 2 MB
  half_t* WpT = (half_t*)(cT16 + (size_t)BB * LL * NN);  // 256 KB
  float* cg0 = (float*)(WpT + (size_t)LL * KT);       // 4 MB
  float* cg1 = cg0 + (size_t)BB * NN * LL;            // 4 MB
  float* ctp0 = cg1 + (size_t)BB * NN * LL;           // 4 MB
  float* ctp1 = ctp0 + (size_t)BB * NN * LL;          // 4 MB
  unsigned short* th16 = (unsigned short*)(ctp1 + (size_t)BB * NN * LL);  // 2 MB
  unsigned short* thq16 = th16 + (size_t)HB * NN * DH;                    // 2 MB
  unsigned short* vt16 = thq16 + (size_t)HB * NN * DH;                    // 2 MB

  k_rowsoftmax<<<NN / 2, 256, 0, stream>>>(E, A16);
  k_prep_c<<<dim3(NN / 64, BB), 256, 0, stream>>>(c, cT16);
  k_prep_w<<<KT / 64, 256, 0, stream>>>(Wp, WpT);
  k_gemm1<<<dim3(NN / 64, BB, 2), 256, 0, stream>>>(A16, cT16, cg0, cg1);
  k_gcn3<<<dim3(NN / 64, BB, 2), 256, 0, stream>>>(E, WpT, bp, c, cg0, cg1, ctp0, ctp1);
  k_prep<<<dim3(HB, NN / 64), 256, 0, stream>>>(state, ctp0, ctp1, th16, thq16, vt16);
  k_attn4<<<dim3(HB, NN / 64), 512, 0, stream>>>(th16, thq16, vt16, out);
}

// Round 12
// 78.770 us; speedup vs baseline: 4.2960x; 1.0425x over previous
//
#include <hip/hip_runtime.h>
#include <hip/hip_bf16.h>

#define NN 2048
#define BB 8
#define LL 64
#define ADA 16
#define DH 16
#define HB 32
#define KT 2048  // GCN GEMM total K = ADA*2*LL

typedef __attribute__((ext_vector_type(4))) short bf16x4;
typedef __attribute__((ext_vector_type(4))) float f32x4;
typedef __attribute__((ext_vector_type(8))) unsigned short ushort8v;
typedef _Float16 half_t;
typedef __attribute__((ext_vector_type(2))) _Float16 halfx2;
typedef __attribute__((ext_vector_type(4))) _Float16 halfx4;
typedef __attribute__((ext_vector_type(8))) _Float16 halfx8;

// __has_builtin(__builtin_amdgcn_mfma_*) is FALSE on the host pass of hipcc's
// dual compile -> guard with __HIP_DEVICE_COMPILE__, parse-only dummy on host.
#if defined(__HIP_DEVICE_COMPILE__)
#if __has_builtin(__builtin_amdgcn_mfma_f32_16x16x16bf16_1k)
#define MFMA16(a, b, c) __builtin_amdgcn_mfma_f32_16x16x16bf16_1k(a, b, c, 0, 0, 0)
#elif __has_builtin(__builtin_amdgcn_mfma_f32_16x16x16_bf16)
#define MFMA16(a, b, c) __builtin_amdgcn_mfma_f32_16x16x16_bf16(a, b, c, 0, 0, 0)
#else
#error "no 16x16x16 bf16 mfma builtin on device"
#endif
#if __has_builtin(__builtin_amdgcn_mfma_f32_16x16x16f16)
#define MFMA16H(a, b, c) __builtin_amdgcn_mfma_f32_16x16x16f16(a, b, c, 0, 0, 0)
#elif __has_builtin(__builtin_amdgcn_mfma_f32_16x16x16_f16)
#define MFMA16H(a, b, c) __builtin_amdgcn_mfma_f32_16x16x16_f16(a, b, c, 0, 0, 0)
#else
#error "no 16x16x16 f16 mfma builtin on device"
#endif
#if __has_builtin(__builtin_amdgcn_exp2f)
#define EXP2F(x) __builtin_amdgcn_exp2f(x)
#else
#define EXP2F(x) exp2f(x)
#endif
#else
#define MFMA16(a, b, c) (c)
#define MFMA16H(a, b, c) (c)
#define EXP2F(x) exp2f(x)
#endif

__device__ inline halfx2 cvt_pk2(float a, float b) {
#if defined(__HIP_DEVICE_COMPILE__) && __has_builtin(__builtin_amdgcn_cvt_pkrtz)
  // builtin returns __fp16 ext_vector(2); bit-cast to our _Float16 vec type
  auto r = __builtin_amdgcn_cvt_pkrtz(a, b);
  return __builtin_bit_cast(halfx2, r);
#else
  halfx2 r;
  r[0] = (_Float16)a;
  r[1] = (_Float16)b;
  return r;
#endif
}

__device__ inline unsigned short f2bf(float x) {
  __hip_bfloat16 h = __float2bfloat16(x);
  return *reinterpret_cast<unsigned short*>(&h);
}
__device__ inline float tanh_fast(float v) {
  return 1.f - 2.f / (__expf(2.f * v) + 1.f);
}

// ---------------- K1: A16 = bf16(rowsoftmax(relu(E E^T))), 4 rows/block ----------------
__global__ __launch_bounds__(256) void k_rowsoftmax(const float* __restrict__ E,
                                                    unsigned short* __restrict__ A16) {
  __shared__ float row[4][NN];   // 32 KB
  __shared__ float red[4][256];  // 4 KB
  const int n = blockIdx.x * 4;
  const int t = threadIdx.x;
  float4 e[4][4];
#pragma unroll
  for (int r = 0; r < 4; ++r) {
    const float4* Er = (const float4*)(E + (size_t)(n + r) * ADA);
#pragma unroll
    for (int j = 0; j < 4; ++j) e[r][j] = Er[j];
  }
  float l[4] = {0.f, 0.f, 0.f, 0.f};
  for (int m = t; m < NN; m += 256) {
    const float4* Em = (const float4*)(E + (size_t)m * ADA);
    float4 ev[4];
#pragma unroll
    for (int j = 0; j < 4; ++j) ev[j] = Em[j];
#pragma unroll
    for (int r = 0; r < 4; ++r) {
      float s = 0.f;
#pragma unroll
      for (int j = 0; j < 4; ++j) {
        s = fmaf(e[r][j].x, ev[j].x, s);
        s = fmaf(e[r][j].y, ev[j].y, s);
        s = fmaf(e[r][j].z, ev[j].z, s);
        s = fmaf(e[r][j].w, ev[j].w, s);
      }
      float p = __expf(fmaxf(s, 0.f) - 20.f);  // fixed shift; cancels in normalize
      row[r][m] = p;
      l[r] += p;
    }
  }
#pragma unroll
  for (int r = 0; r < 4; ++r) red[r][t] = l[r];
  __syncthreads();
  for (int off = 128; off > 0; off >>= 1) {
    if (t < off) {
#pragma unroll
      for (int r = 0; r < 4; ++r) red[r][t] += red[r][t + off];
    }
    __syncthreads();
  }
  float inv[4];
#pragma unroll
  for (int r = 0; r < 4; ++r) inv[r] = 1.f / red[r][0];
  for (int m = t; m < NN; m += 256) {
#pragma unroll
    for (int r = 0; r < 4; ++r)
      A16[(size_t)(n + r) * NN + m] = f2bf(row[r][m] * inv[r]);
  }
}

// ---------------- K2a: cT16[b][o][m] = bf16(c[b][m][o]) ----------------
__global__ __launch_bounds__(256) void k_prep_c(const float* __restrict__ c,
                                                unsigned short* __restrict__ cT16) {
  __shared__ float ld[64][68];
  const int m0 = blockIdx.x * 64;
  const int b = blockIdx.y;
  const int t = threadIdx.x;
  {
    const int r = t & 63, cq = t >> 6;
    const float* cp = c + ((size_t)b * NN + m0 + r) * LL + cq * 16;
#pragma unroll
    for (int u = 0; u < 4; ++u)
      *(float4*)&ld[r][cq * 16 + 4 * u] = *(const float4*)(cp + 4 * u);
  }
  __syncthreads();
  const int o = t & 63, mq = t >> 6;
  unsigned short outv[16];
#pragma unroll
  for (int v = 0; v < 16; ++v) outv[v] = f2bf(ld[mq * 16 + v][o]);
  unsigned short* op = cT16 + ((size_t)b * LL + o) * NN + m0 + mq * 16;
  *(ushort8v*)op = *(const ushort8v*)&outv[0];
  *(ushort8v*)(op + 8) = *(const ushort8v*)&outv[8];
}

// ---------------- K2b: WpT[o][ktot] = fp16(Wp[ktot][o]) ----------------
__global__ __launch_bounds__(256) void k_prep_w(const float* __restrict__ Wp,
                                                half_t* __restrict__ WpT) {
  __shared__ float ld[64][68];
  const int k0 = blockIdx.x * 64;
  const int t = threadIdx.x;
  {
    const int r = t & 63, cq = t >> 6;
    const float* wp = Wp + (size_t)(k0 + r) * LL + cq * 16;
#pragma unroll
    for (int u = 0; u < 4; ++u)
      *(float4*)&ld[r][cq * 16 + 4 * u] = *(const float4*)(wp + 4 * u);
  }
  __syncthreads();
  const int o = t & 63, kq = t >> 6;
  halfx8 h0, h1;
#pragma unroll
  for (int v = 0; v < 8; ++v) {
    h0[v] = (half_t)ld[kq * 16 + v][o];
    h1[v] = (half_t)ld[kq * 16 + 8 + v][o];
  }
  half_t* op = WpT + (size_t)o * KT + k0 + kq * 16;
  *(halfx8*)op = h0;
  *(halfx8*)(op + 8) = h1;
}

// ---------------- K3: cg[b] = A @ c[b], bf16 16x16x16 MFMA (validated), K-split x2 ----------------
__global__ __launch_bounds__(256) void k_gemm1(const unsigned short* __restrict__ A16,
                                               const unsigned short* __restrict__ cT16,
                                               float* __restrict__ cg0,
                                               float* __restrict__ cg1) {
  __shared__ unsigned short sA[64][72];
  __shared__ unsigned short sB[64][72];
  const int t = threadIdx.x;
  const int n0 = blockIdx.x * 64;
  const int b = blockIdx.y;
  const int kh = blockIdx.z;
  const int wv = t >> 6, lane = t & 63;
  const int lr = lane & 15, lg = lane >> 4;
  const unsigned short* cb = cT16 + (size_t)b * LL * NN;
  const int sr = t >> 2, sc = (t & 3) * 16;
  f32x4 acc[4];
#pragma unroll
  for (int ot = 0; ot < 4; ++ot) acc[ot] = (f32x4){0.f, 0.f, 0.f, 0.f};

  for (int k0 = kh * (NN / 2); k0 < (kh + 1) * (NN / 2); k0 += 64) {
    __syncthreads();
    {
      const unsigned short* ga = A16 + (size_t)(n0 + sr) * NN + k0 + sc;
      *(ushort8v*)&sA[sr][sc] = *(const ushort8v*)ga;
      *(ushort8v*)&sA[sr][sc + 8] = *(const ushort8v*)(ga + 8);
      const unsigned short* gb = cb + (size_t)sr * NN + k0 + sc;
      *(ushort8v*)&sB[sr][sc] = *(const ushort8v*)gb;
      *(ushort8v*)&sB[sr][sc + 8] = *(const ushort8v*)(gb + 8);
    }
    __syncthreads();
#pragma unroll
    for (int ks = 0; ks < 4; ++ks) {
      bf16x4 a = *(const bf16x4*)&sA[16 * wv + lr][ks * 16 + 4 * lg];
#pragma unroll
      for (int ot = 0; ot < 4; ++ot) {
        bf16x4 bq = *(const bf16x4*)&sB[ot * 16 + lr][ks * 16 + 4 * lg];
        acc[ot] = MFMA16(a, bq, acc[ot]);
      }
    }
  }
  float* outp = (kh ? cg1 : cg0) + ((size_t)b * NN + n0 + 16 * wv) * LL;
#pragma unroll
  for (int ot = 0; ot < 4; ++ot)
#pragma unroll
    for (int reg = 0; reg < 4; ++reg)
      outp[(size_t)(4 * lg + reg) * LL + ot * 16 + lr] = acc[ot][reg];
}

// ---------------- K4: ctp[dh] = sum_{d in half} E[n,d]*(xg @ Wp[d]) (+bias in dh0) ----------------
// E folded into A-operand (per-lane scalar). fp16 16x16x16 MFMA. sW width 136 (R8 fix).
__global__ __launch_bounds__(256) void k_gcn3(const float* __restrict__ E,
                                              const half_t* __restrict__ WpT,
                                              const float* __restrict__ bp,
                                              const float* __restrict__ c,
                                              const float* __restrict__ cg0,
                                              const float* __restrict__ cg1,
                                              float* __restrict__ ctp0,
                                              float* __restrict__ ctp1) {
  __shared__ half_t sW[64][136];  // 128 data cols + 8 pad (17.4 KB)
  __shared__ float sE[64][17];
  __shared__ float sbp[16][64];
  const int t = threadIdx.x;
  const int n0 = blockIdx.x * 64;
  const int b = blockIdx.y;
  const int dh = blockIdx.z;
  const int wv = t >> 6, lane = t & 63;
  const int lr = lane & 15, lg = lane >> 4;
  {
    const int r = t >> 2, dq = (t & 3) * 4;
    float4 ev = *(const float4*)(E + (size_t)(n0 + r) * ADA + dq);
    sE[r][dq + 0] = ev.x; sE[r][dq + 1] = ev.y;
    sE[r][dq + 2] = ev.z; sE[r][dq + 3] = ev.w;
    const int bi = t * 4;
    *(float4*)&sbp[bi >> 6][bi & 63] = *(const float4*)(bp + bi);
  }
  // x (c | cg0+cg1) into registers. A-frag row = lr, k = 4*lg+j per 16-k tile.
  float xr[8][4];
  {
    const size_t rbase = ((size_t)b * NN + n0 + 16 * wv + lr) * LL;
#pragma unroll
    for (int q = 0; q < 4; ++q) {
      float4 v = *(const float4*)(c + rbase + q * 16 + 4 * lg);
      xr[q][0] = v.x; xr[q][1] = v.y; xr[q][2] = v.z; xr[q][3] = v.w;
    }
#pragma unroll
    for (int q = 0; q < 4; ++q) {
      float4 a = *(const float4*)(cg0 + rbase + q * 16 + 4 * lg);
      float4 b2 = *(const float4*)(cg1 + rbase + q * 16 + 4 * lg);
      xr[4 + q][0] = a.x + b2.x; xr[4 + q][1] = a.y + b2.y;
      xr[4 + q][2] = a.z + b2.z; xr[4 + q][3] = a.w + b2.w;
    }
  }
  __syncthreads();
  // acc init: bias (dh==0) or zero; D rows = 16wv + 4lg + reg, cols = ot*16+lr
  f32x4 acc[4];
  if (dh == 0) {
#pragma unroll
    for (int ot = 0; ot < 4; ++ot) {
      f32x4 s = (f32x4){0.f, 0.f, 0.f, 0.f};
#pragma unroll
      for (int d = 0; d < ADA; ++d) {
        const float bpv = sbp[d][ot * 16 + lr];
#pragma unroll
        for (int reg = 0; reg < 4; ++reg)
          s[reg] = fmaf(sE[16 * wv + 4 * lg + reg][d], bpv, s[reg]);
      }
      acc[ot] = s;
    }
  } else {
#pragma unroll
    for (int ot = 0; ot < 4; ++ot) acc[ot] = (f32x4){0.f, 0.f, 0.f, 0.f};
  }
  // W staging: thread covers o-row so, 8-half chunks (sq+4u)
  const int so = t >> 2, sq = t & 3;
  halfx8 wreg[4];
  {
    const half_t* p = WpT + (size_t)so * KT + (size_t)(dh * 8) * 128;
#pragma unroll
    for (int u = 0; u < 4; ++u) wreg[u] = *(const halfx8*)(p + (sq + 4 * u) * 8);
  }
  for (int dd = 0; dd < 8; ++dd) {
    __syncthreads();  // previous iteration's MFMAs done with sW
#pragma unroll
    for (int u = 0; u < 4; ++u) *(halfx8*)&sW[so][(sq + 4 * u) * 8] = wreg[u];
    __syncthreads();  // sW ready
    if (dd < 7) {
      const half_t* p = WpT + (size_t)so * KT + (size_t)(dh * 8 + dd + 1) * 128;
#pragma unroll
      for (int u = 0; u < 4; ++u) wreg[u] = *(const halfx8*)(p + (sq + 4 * u) * 8);
    }
    const float e = sE[16 * wv + lr][dh * 8 + dd];
    halfx4 af[8];
#pragma unroll
    for (int kt = 0; kt < 8; ++kt)
#pragma unroll
      for (int j = 0; j < 4; ++j) af[kt][j] = (half_t)(e * xr[kt][j]);
#pragma unroll
    for (int kt = 0; kt < 8; ++kt) {
#pragma unroll
      for (int ot = 0; ot < 4; ++ot) {
        halfx4 bq = *(const halfx4*)&sW[ot * 16 + lr][kt * 16 + 4 * lg];
        acc[ot] = MFMA16H(af[kt], bq, acc[ot]);
      }
    }
  }
  float* op = (dh ? ctp1 : ctp0) + ((size_t)b * NN + n0 + 16 * wv) * LL;
#pragma unroll
  for (int ot = 0; ot < 4; ++ot)
#pragma unroll
    for (int reg = 0; reg < 4; ++reg)
      op[(size_t)(4 * lg + reg) * LL + ot * 16 + lr] = acc[ot][reg];
}

// ---------------- K5: prep — tanh(ctp0+ctp1) -> vt16h; th16h (K), thq16h (Q scaled), all fp16 ----------------
__global__ __launch_bounds__(256) void k_prep(const float* __restrict__ state,
                                              const float* __restrict__ ctp0,
                                              const float* __restrict__ ctp1,
                                              half_t* __restrict__ th16h,
                                              half_t* __restrict__ thq16h,
                                              half_t* __restrict__ vt16h) {
  __shared__ half_t vt[16][68];
  const int hb = blockIdx.x;
  const int h = hb >> 3, b = hb & 7;
  const int n0 = blockIdx.y * 64;
  const int t = threadIdx.x;
  const int r = t >> 2, dq = t & 3;
  const float QS = 0.25f * 1.4426950408889634f;  // fold score scale + log2(e) into Q
  const float* sp = state + ((size_t)b * NN + n0 + r) * LL + h * DH + 4 * dq;
  float4 sv = *(const float4*)sp;
  halfx4 tk;
  tk[0] = (half_t)sv.x; tk[1] = (half_t)sv.y; tk[2] = (half_t)sv.z; tk[3] = (half_t)sv.w;
  *(halfx4*)(th16h + ((size_t)hb * NN + n0 + r) * DH + 4 * dq) = tk;
  halfx4 tq;
  tq[0] = (half_t)(QS * sv.x); tq[1] = (half_t)(QS * sv.y);
  tq[2] = (half_t)(QS * sv.z); tq[3] = (half_t)(QS * sv.w);
  *(halfx4*)(thq16h + ((size_t)hb * NN + n0 + r) * DH + 4 * dq) = tq;
  const size_t cidx = ((size_t)b * NN + n0 + r) * LL + h * DH + 4 * dq;
  float4 p0 = *(const float4*)(ctp0 + cidx);
  float4 p1 = *(const float4*)(ctp1 + cidx);
  vt[4 * dq + 0][r] = (half_t)tanh_fast(p0.x + p1.x);
  vt[4 * dq + 1][r] = (half_t)tanh_fast(p0.y + p1.y);
  vt[4 * dq + 2][r] = (half_t)tanh_fast(p0.z + p1.z);
  vt[4 * dq + 3][r] = (half_t)tanh_fast(p0.w + p1.w);
  __syncthreads();
  const int d = t >> 4, mq = t & 15;
  halfx4 o;
  o[0] = vt[d][4 * mq + 0]; o[1] = vt[d][4 * mq + 1];
  o[2] = vt[d][4 * mq + 2]; o[3] = vt[d][4 * mq + 3];
  *(halfx4*)(vt16h + ((size_t)hb * DH + d) * NN + n0 + 4 * mq) = o;
}

// ---------------- K6: fp16 MFMA attention — shift-8 softmax via MFMA C-init (fp16-safe) ----------------
__global__ __launch_bounds__(512, 8) void k_attn4(const half_t* __restrict__ th16h,
                                                  const half_t* __restrict__ thq16h,
                                                  const half_t* __restrict__ vt16h,
                                                  float* __restrict__ out) {
  __shared__ float dnum[8][4][16][16];  // [wave][frag][qrow][d]  32 KB
  __shared__ float dden[8][4][16];      // [wave][frag][q]        2 KB
  const int hb = blockIdx.x;
  const int h = hb >> 3, b = hb & 7;
  const int wv = threadIdx.x >> 6, lane = threadIdx.x & 63;
  const int q0 = blockIdx.y * 64;
  const int lr = lane & 15, lg = lane >> 4;
  const half_t* th = th16h + (size_t)hb * NN * DH;
  const half_t* thq = thq16h + (size_t)hb * NN * DH;
  const half_t* vrow = vt16h + ((size_t)hb * DH + lr) * NN;  // V^T row d=lr
  halfx4 qf[4];
#pragma unroll
  for (int f = 0; f < 4; ++f)
    qf[f] = *(const halfx4*)(thq + (size_t)(q0 + 16 * f + lr) * DH + 4 * lg);
  const f32x4 zero = {0.f, 0.f, 0.f, 0.f};
  // shift-8 softmax: scores in exp2 units; subtract 8*log2(e) so P=e^(S-8) <= ~e^6,
  // safely inside fp16 range (fixes R11's fp16-clamp num/den inconsistency). Free via C-init.
  const float SH = 8.f * 1.4426950408889634f;
  const f32x4 shiftv = {-SH, -SH, -SH, -SH};
  f32x4 acc[4];
  float den[4];
#pragma unroll
  for (int f = 0; f < 4; ++f) { acc[f] = zero; den[f] = 0.f; }

  const int mb = wv * (NN / 8);  // this wave's 256-row m-slice
  halfx4 kf = *(const halfx4*)(th + (size_t)(mb + lr) * DH + 4 * lg);
  halfx4 vf = *(const halfx4*)(vrow + mb + 4 * lg);
  for (int mt = 0; mt < NN / 128; ++mt) {  // 16 tiles of 16
    halfx4 kf_n = kf, vf_n = vf;
    if (mt < NN / 128 - 1) {
      const int mn = mb + (mt + 1) * 16;
      kf_n = *(const halfx4*)(th + (size_t)(mn + lr) * DH + 4 * lg);
      vf_n = *(const halfx4*)(vrow + mn + 4 * lg);
    }
#pragma unroll
    for (int f = 0; f < 4; ++f) {
      f32x4 s = MFMA16H(kf, qf[f], shiftv);  // lane: col q, rows m; pre-shifted
      float p0 = EXP2F(s[0]), p1 = EXP2F(s[1]), p2 = EXP2F(s[2]), p3 = EXP2F(s[3]);
      den[f] += (p0 + p1) + (p2 + p3);
      halfx2 lo = cvt_pk2(p0, p1), hi = cvt_pk2(p2, p3);
      halfx4 pf;
      pf[0] = lo[0]; pf[1] = lo[1]; pf[2] = hi[0]; pf[3] = hi[1];
      acc[f] = MFMA16H(pf, vf, acc[f]);  // lane: col d=lr, rows q=16f+4lg+reg
    }
    kf = kf_n; vf = vf_n;
  }
#pragma unroll
  for (int f = 0; f < 4; ++f) {
    den[f] += __shfl_xor(den[f], 16);
    den[f] += __shfl_xor(den[f], 32);
  }
#pragma unroll
  for (int f = 0; f < 4; ++f) {
#pragma unroll
    for (int reg = 0; reg < 4; ++reg) dnum[wv][f][4 * lg + reg][lr] = acc[f][reg];
    if (lane < 16) dden[wv][f][lane] = den[f];
  }
  __syncthreads();
  // combine 8 wave-partials; 512 threads -> (frag, qrow, d-pair)
  const int t = threadIdx.x;
  const int f = t >> 7, rem = t & 127;
  const int r = rem >> 3, du = (rem & 7) * 2;
  float n0s = 0.f, n1s = 0.f, ds = 0.f;
#pragma unroll
  for (int w = 0; w < 8; ++w) {
    n0s += dnum[w][f][r][du];
    n1s += dnum[w][f][r][du + 1];
    ds += dden[w][f][r];
  }
  const float inv = -1.f / ds;
  float2 o = make_float2(n0s * inv, n1s * inv);
  *(float2*)(out + ((size_t)b * NN + q0 + 16 * f + r) * LL + h * DH + du) = o;
}

extern "C" void kernel_launch(void* const* d_in, const int* in_sizes, int n_in,
                              void* d_out, int out_size, void* d_ws, size_t ws_size,
                              hipStream_t stream) {
  const float* c = (const float*)d_in[0];
  const float* state = (const float*)d_in[3];
  const float* E = (const float*)d_in[4];
  const float* Wp = (const float*)d_in[13];
  const float* bp = (const float*)d_in[14];
  float* out = (float*)d_out;

  unsigned short* A16 = (unsigned short*)d_ws;        // 2048*2048 bf16 = 8 MB
  unsigned short* cT16 = A16 + (size_t)NN * NN;       // 2 MB
  half_t* WpT = (half_t*)(cT16 + (size_t)BB * LL * NN);  // 256 KB
  float* cg0 = (float*)(WpT + (size_t)LL * KT);       // 4 MB
  float* cg1 = cg0 + (size_t)BB * NN * LL;            // 4 MB
  float* ctp0 = cg1 + (size_t)BB * NN * LL;           // 4 MB
  float* ctp1 = ctp0 + (size_t)BB * NN * LL;          // 4 MB
  half_t* th16h = (half_t*)(ctp1 + (size_t)BB * NN * LL);  // 2 MB
  half_t* thq16h = th16h + (size_t)HB * NN * DH;           // 2 MB
  half_t* vt16h = thq16h + (size_t)HB * NN * DH;           // 2 MB

  k_rowsoftmax<<<NN / 4, 256, 0, stream>>>(E, A16);
  k_prep_c<<<dim3(NN / 64, BB), 256, 0, stream>>>(c, cT16);
  k_prep_w<<<KT / 64, 256, 0, stream>>>(Wp, WpT);
  k_gemm1<<<dim3(NN / 64, BB, 2), 256, 0, stream>>>(A16, cT16, cg0, cg1);
  k_gcn3<<<dim3(NN / 64, BB, 2), 256, 0, stream>>>(E, WpT, bp, c, cg0, cg1, ctp0, ctp1);
  k_prep<<<dim3(HB, NN / 64), 256, 0, stream>>>(state, ctp0, ctp1, th16h, thq16h, vt16h);
  k_attn4<<<dim3(HB, NN / 64), 512, 0, stream>>>(th16h, thq16h, vt16h, out);
}

// Round 13
// 76.408 us; speedup vs baseline: 4.4288x; 1.0309x over previous
//
#include <hip/hip_runtime.h>
#include <hip/hip_bf16.h>

#define NN 2048
#define BB 8
#define LL 64
#define ADA 16
#define DH 16
#define HB 32
#define KT 2048  // GCN GEMM total K = ADA*2*LL

typedef __attribute__((ext_vector_type(4))) short bf16x4;
typedef __attribute__((ext_vector_type(4))) float f32x4;
typedef __attribute__((ext_vector_type(8))) unsigned short ushort8v;
typedef _Float16 half_t;
typedef __attribute__((ext_vector_type(2))) _Float16 halfx2;
typedef __attribute__((ext_vector_type(4))) _Float16 halfx4;
typedef __attribute__((ext_vector_type(8))) _Float16 halfx8;

// __has_builtin(__builtin_amdgcn_mfma_*) is FALSE on the host pass of hipcc's
// dual compile -> guard with __HIP_DEVICE_COMPILE__, parse-only dummy on host.
#if defined(__HIP_DEVICE_COMPILE__)
#if __has_builtin(__builtin_amdgcn_mfma_f32_16x16x16bf16_1k)
#define MFMA16(a, b, c) __builtin_amdgcn_mfma_f32_16x16x16bf16_1k(a, b, c, 0, 0, 0)
#elif __has_builtin(__builtin_amdgcn_mfma_f32_16x16x16_bf16)
#define MFMA16(a, b, c) __builtin_amdgcn_mfma_f32_16x16x16_bf16(a, b, c, 0, 0, 0)
#else
#error "no 16x16x16 bf16 mfma builtin on device"
#endif
#if __has_builtin(__builtin_amdgcn_mfma_f32_16x16x16f16)
#define MFMA16H(a, b, c) __builtin_amdgcn_mfma_f32_16x16x16f16(a, b, c, 0, 0, 0)
#elif __has_builtin(__builtin_amdgcn_mfma_f32_16x16x16_f16)
#define MFMA16H(a, b, c) __builtin_amdgcn_mfma_f32_16x16x16_f16(a, b, c, 0, 0, 0)
#else
#error "no 16x16x16 f16 mfma builtin on device"
#endif
#if __has_builtin(__builtin_amdgcn_exp2f)
#define EXP2F(x) __builtin_amdgcn_exp2f(x)
#else
#define EXP2F(x) exp2f(x)
#endif
#else
#define MFMA16(a, b, c) (c)
#define MFMA16H(a, b, c) (c)
#define EXP2F(x) exp2f(x)
#endif

__device__ inline halfx2 cvt_pk2(float a, float b) {
#if defined(__HIP_DEVICE_COMPILE__) && __has_builtin(__builtin_amdgcn_cvt_pkrtz)
  // builtin returns __fp16 ext_vector(2); bit-cast to our _Float16 vec type
  auto r = __builtin_amdgcn_cvt_pkrtz(a, b);
  return __builtin_bit_cast(halfx2, r);
#else
  halfx2 r;
  r[0] = (_Float16)a;
  r[1] = (_Float16)b;
  return r;
#endif
}

__device__ inline unsigned short f2bf(float x) {
  __hip_bfloat16 h = __float2bfloat16(x);
  return *reinterpret_cast<unsigned short*>(&h);
}
__device__ inline float tanh_fast(float v) {
  return 1.f - 2.f / (__expf(2.f * v) + 1.f);
}

// ---------------- K1: A16 = bf16(rowsoftmax(relu(E E^T))), 4 rows/block ----------------
__global__ __launch_bounds__(256) void k_rowsoftmax(const float* __restrict__ E,
                                                    unsigned short* __restrict__ A16) {
  __shared__ float row[4][NN];   // 32 KB
  __shared__ float red[4][256];  // 4 KB
  const int n = blockIdx.x * 4;
  const int t = threadIdx.x;
  float4 e[4][4];
#pragma unroll
  for (int r = 0; r < 4; ++r) {
    const float4* Er = (const float4*)(E + (size_t)(n + r) * ADA);
#pragma unroll
    for (int j = 0; j < 4; ++j) e[r][j] = Er[j];
  }
  float l[4] = {0.f, 0.f, 0.f, 0.f};
  for (int m = t; m < NN; m += 256) {
    const float4* Em = (const float4*)(E + (size_t)m * ADA);
    float4 ev[4];
#pragma unroll
    for (int j = 0; j < 4; ++j) ev[j] = Em[j];
#pragma unroll
    for (int r = 0; r < 4; ++r) {
      float s = 0.f;
#pragma unroll
      for (int j = 0; j < 4; ++j) {
        s = fmaf(e[r][j].x, ev[j].x, s);
        s = fmaf(e[r][j].y, ev[j].y, s);
        s = fmaf(e[r][j].z, ev[j].z, s);
        s = fmaf(e[r][j].w, ev[j].w, s);
      }
      float p = __expf(fmaxf(s, 0.f) - 20.f);  // fixed shift; cancels in normalize
      row[r][m] = p;
      l[r] += p;
    }
  }
#pragma unroll
  for (int r = 0; r < 4; ++r) red[r][t] = l[r];
  __syncthreads();
  for (int off = 128; off > 0; off >>= 1) {
    if (t < off) {
#pragma unroll
      for (int r = 0; r < 4; ++r) red[r][t] += red[r][t + off];
    }
    __syncthreads();
  }
  float inv[4];
#pragma unroll
  for (int r = 0; r < 4; ++r) inv[r] = 1.f / red[r][0];
  for (int m = t; m < NN; m += 256) {
#pragma unroll
    for (int r = 0; r < 4; ++r)
      A16[(size_t)(n + r) * NN + m] = f2bf(row[r][m] * inv[r]);
  }
}

// ---------------- K2a: cT16[b][o][m] = bf16(c[b][m][o]) ----------------
__global__ __launch_bounds__(256) void k_prep_c(const float* __restrict__ c,
                                                unsigned short* __restrict__ cT16) {
  __shared__ float ld[64][68];
  const int m0 = blockIdx.x * 64;
  const int b = blockIdx.y;
  const int t = threadIdx.x;
  {
    const int r = t & 63, cq = t >> 6;
    const float* cp = c + ((size_t)b * NN + m0 + r) * LL + cq * 16;
#pragma unroll
    for (int u = 0; u < 4; ++u)
      *(float4*)&ld[r][cq * 16 + 4 * u] = *(const float4*)(cp + 4 * u);
  }
  __syncthreads();
  const int o = t & 63, mq = t >> 6;
  unsigned short outv[16];
#pragma unroll
  for (int v = 0; v < 16; ++v) outv[v] = f2bf(ld[mq * 16 + v][o]);
  unsigned short* op = cT16 + ((size_t)b * LL + o) * NN + m0 + mq * 16;
  *(ushort8v*)op = *(const ushort8v*)&outv[0];
  *(ushort8v*)(op + 8) = *(const ushort8v*)&outv[8];
}

// ---------------- K2b: WpT[o][ktot] = fp16(Wp[ktot][o]) ----------------
__global__ __launch_bounds__(256) void k_prep_w(const float* __restrict__ Wp,
                                                half_t* __restrict__ WpT) {
  __shared__ float ld[64][68];
  const int k0 = blockIdx.x * 64;
  const int t = threadIdx.x;
  {
    const int r = t & 63, cq = t >> 6;
    const float* wp = Wp + (size_t)(k0 + r) * LL + cq * 16;
#pragma unroll
    for (int u = 0; u < 4; ++u)
      *(float4*)&ld[r][cq * 16 + 4 * u] = *(const float4*)(wp + 4 * u);
  }
  __syncthreads();
  const int o = t & 63, kq = t >> 6;
  halfx8 h0, h1;
#pragma unroll
  for (int v = 0; v < 8; ++v) {
    h0[v] = (half_t)ld[kq * 16 + v][o];
    h1[v] = (half_t)ld[kq * 16 + 8 + v][o];
  }
  half_t* op = WpT + (size_t)o * KT + k0 + kq * 16;
  *(halfx8*)op = h0;
  *(halfx8*)(op + 8) = h1;
}

// ---------------- K3: cg[b] = A @ c[b], bf16 16x16x16 MFMA (validated), K-split x2 ----------------
__global__ __launch_bounds__(256) void k_gemm1(const unsigned short* __restrict__ A16,
                                               const unsigned short* __restrict__ cT16,
                                               float* __restrict__ cg0,
                                               float* __restrict__ cg1) {
  __shared__ unsigned short sA[64][72];
  __shared__ unsigned short sB[64][72];
  const int t = threadIdx.x;
  const int n0 = blockIdx.x * 64;
  const int b = blockIdx.y;
  const int kh = blockIdx.z;
  const int wv = t >> 6, lane = t & 63;
  const int lr = lane & 15, lg = lane >> 4;
  const unsigned short* cb = cT16 + (size_t)b * LL * NN;
  const int sr = t >> 2, sc = (t & 3) * 16;
  f32x4 acc[4];
#pragma unroll
  for (int ot = 0; ot < 4; ++ot) acc[ot] = (f32x4){0.f, 0.f, 0.f, 0.f};

  for (int k0 = kh * (NN / 2); k0 < (kh + 1) * (NN / 2); k0 += 64) {
    __syncthreads();
    {
      const unsigned short* ga = A16 + (size_t)(n0 + sr) * NN + k0 + sc;
      *(ushort8v*)&sA[sr][sc] = *(const ushort8v*)ga;
      *(ushort8v*)&sA[sr][sc + 8] = *(const ushort8v*)(ga + 8);
      const unsigned short* gb = cb + (size_t)sr * NN + k0 + sc;
      *(ushort8v*)&sB[sr][sc] = *(const ushort8v*)gb;
      *(ushort8v*)&sB[sr][sc + 8] = *(const ushort8v*)(gb + 8);
    }
    __syncthreads();
#pragma unroll
    for (int ks = 0; ks < 4; ++ks) {
      bf16x4 a = *(const bf16x4*)&sA[16 * wv + lr][ks * 16 + 4 * lg];
#pragma unroll
      for (int ot = 0; ot < 4; ++ot) {
        bf16x4 bq = *(const bf16x4*)&sB[ot * 16 + lr][ks * 16 + 4 * lg];
        acc[ot] = MFMA16(a, bq, acc[ot]);
      }
    }
  }
  float* outp = (kh ? cg1 : cg0) + ((size_t)b * NN + n0 + 16 * wv) * LL;
#pragma unroll
  for (int ot = 0; ot < 4; ++ot)
#pragma unroll
    for (int reg = 0; reg < 4; ++reg)
      outp[(size_t)(4 * lg + reg) * LL + ot * 16 + lr] = acc[ot][reg];
}

// ---------------- K4: ctp[dh] = sum_{d in half} E[n,d]*(xg @ Wp[d]) (+bias in dh0) ----------------
// E folded into A-operand (per-lane scalar). fp16 16x16x16 MFMA. sW width 136 (R8 fix).
__global__ __launch_bounds__(256) void k_gcn3(const float* __restrict__ E,
                                              const half_t* __restrict__ WpT,
                                              const float* __restrict__ bp,
                                              const float* __restrict__ c,
                                              const float* __restrict__ cg0,
                                              const float* __restrict__ cg1,
                                              float* __restrict__ ctp0,
                                              float* __restrict__ ctp1) {
  __shared__ half_t sW[64][136];  // 128 data cols + 8 pad (17.4 KB)
  __shared__ float sE[64][17];
  __shared__ float sbp[16][64];
  const int t = threadIdx.x;
  const int n0 = blockIdx.x * 64;
  const int b = blockIdx.y;
  const int dh = blockIdx.z;
  const int wv = t >> 6, lane = t & 63;
  const int lr = lane & 15, lg = lane >> 4;
  {
    const int r = t >> 2, dq = (t & 3) * 4;
    float4 ev = *(const float4*)(E + (size_t)(n0 + r) * ADA + dq);
    sE[r][dq + 0] = ev.x; sE[r][dq + 1] = ev.y;
    sE[r][dq + 2] = ev.z; sE[r][dq + 3] = ev.w;
    const int bi = t * 4;
    *(float4*)&sbp[bi >> 6][bi & 63] = *(const float4*)(bp + bi);
  }
  // x (c | cg0+cg1) into registers. A-frag row = lr, k = 4*lg+j per 16-k tile.
  float xr[8][4];
  {
    const size_t rbase = ((size_t)b * NN + n0 + 16 * wv + lr) * LL;
#pragma unroll
    for (int q = 0; q < 4; ++q) {
      float4 v = *(const float4*)(c + rbase + q * 16 + 4 * lg);
      xr[q][0] = v.x; xr[q][1] = v.y; xr[q][2] = v.z; xr[q][3] = v.w;
    }
#pragma unroll
    for (int q = 0; q < 4; ++q) {
      float4 a = *(const float4*)(cg0 + rbase + q * 16 + 4 * lg);
      float4 b2 = *(const float4*)(cg1 + rbase + q * 16 + 4 * lg);
      xr[4 + q][0] = a.x + b2.x; xr[4 + q][1] = a.y + b2.y;
      xr[4 + q][2] = a.z + b2.z; xr[4 + q][3] = a.w + b2.w;
    }
  }
  __syncthreads();
  // acc init: bias (dh==0) or zero; D rows = 16wv + 4lg + reg, cols = ot*16+lr
  f32x4 acc[4];
  if (dh == 0) {
#pragma unroll
    for (int ot = 0; ot < 4; ++ot) {
      f32x4 s = (f32x4){0.f, 0.f, 0.f, 0.f};
#pragma unroll
      for (int d = 0; d < ADA; ++d) {
        const float bpv = sbp[d][ot * 16 + lr];
#pragma unroll
        for (int reg = 0; reg < 4; ++reg)
          s[reg] = fmaf(sE[16 * wv + 4 * lg + reg][d], bpv, s[reg]);
      }
      acc[ot] = s;
    }
  } else {
#pragma unroll
    for (int ot = 0; ot < 4; ++ot) acc[ot] = (f32x4){0.f, 0.f, 0.f, 0.f};
  }
  // W staging: thread covers o-row so, 8-half chunks (sq+4u)
  const int so = t >> 2, sq = t & 3;
  halfx8 wreg[4];
  {
    const half_t* p = WpT + (size_t)so * KT + (size_t)(dh * 8) * 128;
#pragma unroll
    for (int u = 0; u < 4; ++u) wreg[u] = *(const halfx8*)(p + (sq + 4 * u) * 8);
  }
  for (int dd = 0; dd < 8; ++dd) {
    __syncthreads();  // previous iteration's MFMAs done with sW
#pragma unroll
    for (int u = 0; u < 4; ++u) *(halfx8*)&sW[so][(sq + 4 * u) * 8] = wreg[u];
    __syncthreads();  // sW ready
    if (dd < 7) {
      const half_t* p = WpT + (size_t)so * KT + (size_t)(dh * 8 + dd + 1) * 128;
#pragma unroll
      for (int u = 0; u < 4; ++u) wreg[u] = *(const halfx8*)(p + (sq + 4 * u) * 8);
    }
    const float e = sE[16 * wv + lr][dh * 8 + dd];
    halfx4 af[8];
#pragma unroll
    for (int kt = 0; kt < 8; ++kt)
#pragma unroll
      for (int j = 0; j < 4; ++j) af[kt][j] = (half_t)(e * xr[kt][j]);
#pragma unroll
    for (int kt = 0; kt < 8; ++kt) {
#pragma unroll
      for (int ot = 0; ot < 4; ++ot) {
        halfx4 bq = *(const halfx4*)&sW[ot * 16 + lr][kt * 16 + 4 * lg];
        acc[ot] = MFMA16H(af[kt], bq, acc[ot]);
      }
    }
  }
  float* op = (dh ? ctp1 : ctp0) + ((size_t)b * NN + n0 + 16 * wv) * LL;
#pragma unroll
  for (int ot = 0; ot < 4; ++ot)
#pragma unroll
    for (int reg = 0; reg < 4; ++reg)
      op[(size_t)(4 * lg + reg) * LL + ot * 16 + lr] = acc[ot][reg];
}

// ---------------- K5: prep — tanh(ctp0+ctp1) -> vt16h; th16h (K), thq16h (Q scaled), all fp16 ----------------
__global__ __launch_bounds__(256) void k_prep(const float* __restrict__ state,
                                              const float* __restrict__ ctp0,
                                              const float* __restrict__ ctp1,
                                              half_t* __restrict__ th16h,
                                              half_t* __restrict__ thq16h,
                                              half_t* __restrict__ vt16h) {
  __shared__ half_t vt[16][68];
  const int hb = blockIdx.x;
  const int h = hb >> 3, b = hb & 7;
  const int n0 = blockIdx.y * 64;
  const int t = threadIdx.x;
  const int r = t >> 2, dq = t & 3;
  const float QS = 0.25f * 1.4426950408889634f;  // fold score scale + log2(e) into Q
  const float* sp = state + ((size_t)b * NN + n0 + r) * LL + h * DH + 4 * dq;
  float4 sv = *(const float4*)sp;
  halfx4 tk;
  tk[0] = (half_t)sv.x; tk[1] = (half_t)sv.y; tk[2] = (half_t)sv.z; tk[3] = (half_t)sv.w;
  *(halfx4*)(th16h + ((size_t)hb * NN + n0 + r) * DH + 4 * dq) = tk;
  halfx4 tq;
  tq[0] = (half_t)(QS * sv.x); tq[1] = (half_t)(QS * sv.y);
  tq[2] = (half_t)(QS * sv.z); tq[3] = (half_t)(QS * sv.w);
  *(halfx4*)(thq16h + ((size_t)hb * NN + n0 + r) * DH + 4 * dq) = tq;
  const size_t cidx = ((size_t)b * NN + n0 + r) * LL + h * DH + 4 * dq;
  float4 p0 = *(const float4*)(ctp0 + cidx);
  float4 p1 = *(const float4*)(ctp1 + cidx);
  vt[4 * dq + 0][r] = (half_t)tanh_fast(p0.x + p1.x);
  vt[4 * dq + 1][r] = (half_t)tanh_fast(p0.y + p1.y);
  vt[4 * dq + 2][r] = (half_t)tanh_fast(p0.z + p1.z);
  vt[4 * dq + 3][r] = (half_t)tanh_fast(p0.w + p1.w);
  __syncthreads();
  const int d = t >> 4, mq = t & 15;
  halfx4 o;
  o[0] = vt[d][4 * mq + 0]; o[1] = vt[d][4 * mq + 1];
  o[2] = vt[d][4 * mq + 2]; o[3] = vt[d][4 * mq + 3];
  *(halfx4*)(vt16h + ((size_t)hb * DH + d) * NN + n0 + 4 * mq) = o;
}

// ---------------- K6: fp16 MFMA attention — 128 q/block (8 frags/wave), m split 8-way ----------------
// K/V L2-traffic halves vs 64-q blocks; 64 KB LDS reduction buffer reused den->num.
__global__ __launch_bounds__(512, 4) void k_attn5(const half_t* __restrict__ th16h,
                                                  const half_t* __restrict__ thq16h,
                                                  const half_t* __restrict__ vt16h,
                                                  float* __restrict__ out) {
  __shared__ float sred[8][8][16][16];  // 64 KB: phase A den (first 4 KB), phase B num
  float* dfl = &sred[0][0][0][0];
  const int hb = blockIdx.x;
  const int h = hb >> 3, b = hb & 7;
  const int wv = threadIdx.x >> 6, lane = threadIdx.x & 63;
  const int q0 = blockIdx.y * 128;
  const int lr = lane & 15, lg = lane >> 4;
  const half_t* th = th16h + (size_t)hb * NN * DH;
  const half_t* thq = thq16h + (size_t)hb * NN * DH;
  const half_t* vrow = vt16h + ((size_t)hb * DH + lr) * NN;  // V^T row d=lr
  halfx4 qf[8];
#pragma unroll
  for (int f = 0; f < 8; ++f)
    qf[f] = *(const halfx4*)(thq + (size_t)(q0 + 16 * f + lr) * DH + 4 * lg);
  // shift-8 softmax via MFMA C-init (fp16-safe, cancels in num/den)
  const float SH = 8.f * 1.4426950408889634f;
  const f32x4 shiftv = {-SH, -SH, -SH, -SH};
  f32x4 acc[8];
  float den[8];
#pragma unroll
  for (int f = 0; f < 8; ++f) { acc[f] = (f32x4){0.f, 0.f, 0.f, 0.f}; den[f] = 0.f; }

  const int mb = wv * (NN / 8);  // this wave's 256-row m-slice
  halfx4 kf = *(const halfx4*)(th + (size_t)(mb + lr) * DH + 4 * lg);
  halfx4 vf = *(const halfx4*)(vrow + mb + 4 * lg);
  for (int mt = 0; mt < NN / 128; ++mt) {  // 16 tiles of 16
    halfx4 kf_n = kf, vf_n = vf;
    if (mt < NN / 128 - 1) {
      const int mn = mb + (mt + 1) * 16;
      kf_n = *(const halfx4*)(th + (size_t)(mn + lr) * DH + 4 * lg);
      vf_n = *(const halfx4*)(vrow + mn + 4 * lg);
    }
#pragma unroll
    for (int f = 0; f < 8; ++f) {
      f32x4 s = MFMA16H(kf, qf[f], shiftv);  // lane: col q, rows m; pre-shifted
      float p0 = EXP2F(s[0]), p1 = EXP2F(s[1]), p2 = EXP2F(s[2]), p3 = EXP2F(s[3]);
      den[f] += (p0 + p1) + (p2 + p3);
      halfx2 lo = cvt_pk2(p0, p1), hi = cvt_pk2(p2, p3);
      halfx4 pf;
      pf[0] = lo[0]; pf[1] = lo[1]; pf[2] = hi[0]; pf[3] = hi[1];
      acc[f] = MFMA16H(pf, vf, acc[f]);  // lane: col d=lr, rows q=16f+4lg+reg
    }
    kf = kf_n; vf = vf_n;
  }
#pragma unroll
  for (int f = 0; f < 8; ++f) {
    den[f] += __shfl_xor(den[f], 16);
    den[f] += __shfl_xor(den[f], 32);
  }
  // phase A: den partials (8 waves x 8 frags x 16 q = 4 KB of sred)
  if (lane < 16) {
#pragma unroll
    for (int f = 0; f < 8; ++f) dfl[(wv * 8 + f) * 16 + lane] = den[f];
  }
  __syncthreads();
  const int t = threadIdx.x;
  const int fo = t >> 6, ro = (t >> 2) & 15, duo = (t & 3) * 4;
  float ds = 0.f;
#pragma unroll
  for (int w = 0; w < 8; ++w) ds += dfl[(w * 8 + fo) * 16 + ro];
  __syncthreads();  // done reading den region before overwrite
  // phase B: numerator partials
#pragma unroll
  for (int f = 0; f < 8; ++f) {
#pragma unroll
    for (int reg = 0; reg < 4; ++reg) sred[wv][f][4 * lg + reg][lr] = acc[f][reg];
  }
  __syncthreads();
  float4 ns = make_float4(0.f, 0.f, 0.f, 0.f);
#pragma unroll
  for (int w = 0; w < 8; ++w) {
    float4 v = *(const float4*)&sred[w][fo][ro][duo];
    ns.x += v.x; ns.y += v.y; ns.z += v.z; ns.w += v.w;
  }
  const float inv = -1.f / ds;
  float4 o = make_float4(ns.x * inv, ns.y * inv, ns.z * inv, ns.w * inv);
  *(float4*)(out + ((size_t)b * NN + q0 + 16 * fo + ro) * LL + h * DH + duo) = o;
}

extern "C" void kernel_launch(void* const* d_in, const int* in_sizes, int n_in,
                              void* d_out, int out_size, void* d_ws, size_t ws_size,
                              hipStream_t stream) {
  const float* c = (const float*)d_in[0];
  const float* state = (const float*)d_in[3];
  const float* E = (const float*)d_in[4];
  const float* Wp = (const float*)d_in[13];
  const float* bp = (const float*)d_in[14];
  float* out = (float*)d_out;

  unsigned short* A16 = (unsigned short*)d_ws;        // 2048*2048 bf16 = 8 MB
  unsigned short* cT16 = A16 + (size_t)NN * NN;       // 2 MB
  half_t* WpT = (half_t*)(cT16 + (size_t)BB * LL * NN);  // 256 KB
  float* cg0 = (float*)(WpT + (size_t)LL * KT);       // 4 MB
  float* cg1 = cg0 + (size_t)BB * NN * LL;            // 4 MB
  float* ctp0 = cg1 + (size_t)BB * NN * LL;           // 4 MB
  float* ctp1 = ctp0 + (size_t)BB * NN * LL;          // 4 MB
  half_t* th16h = (half_t*)(ctp1 + (size_t)BB * NN * LL);  // 2 MB
  half_t* thq16h = th16h + (size_t)HB * NN * DH;           // 2 MB
  half_t* vt16h = thq16h + (size_t)HB * NN * DH;           // 2 MB

  k_rowsoftmax<<<NN / 4, 256, 0, stream>>>(E, A16);
  k_prep_c<<<dim3(NN / 64, BB), 256, 0, stream>>>(c, cT16);
  k_prep_w<<<KT / 64, 256, 0, stream>>>(Wp, WpT);
  k_gemm1<<<dim3(NN / 64, BB, 2), 256, 0, stream>>>(A16, cT16, cg0, cg1);
  k_gcn3<<<dim3(NN / 64, BB, 2), 256, 0, stream>>>(E, WpT, bp, c, cg0, cg1, ctp0, ctp1);
  k_prep<<<dim3(HB, NN / 64), 256, 0, stream>>>(state, ctp0, ctp1, th16h, thq16h, vt16h);
  k_attn5<<<dim3(HB, NN / 128), 512, 0, stream>>>(th16h, thq16h, vt16h, out);
}

// Round 14
// 72.781 us; speedup vs baseline: 4.6496x; 1.0498x over previous
//
#include <hip/hip_runtime.h>
#include <hip/hip_bf16.h>

#define NN 2048
#define BB 8
#define LL 64
#define ADA 16
#define DH 16
#define HB 32
#define KT 2048  // GCN GEMM total K = ADA*2*LL

typedef __attribute__((ext_vector_type(4))) short bf16x4;
typedef __attribute__((ext_vector_type(4))) float f32x4;
typedef __attribute__((ext_vector_type(8))) unsigned short ushort8v;
typedef _Float16 half_t;
typedef __attribute__((ext_vector_type(2))) _Float16 halfx2;
typedef __attribute__((ext_vector_type(4))) _Float16 halfx4;
typedef __attribute__((ext_vector_type(8))) _Float16 halfx8;

// __has_builtin(__builtin_amdgcn_mfma_*) is FALSE on the host pass of hipcc's
// dual compile -> guard with __HIP_DEVICE_COMPILE__, parse-only dummy on host.
#if defined(__HIP_DEVICE_COMPILE__)
#if __has_builtin(__builtin_amdgcn_mfma_f32_16x16x16bf16_1k)
#define MFMA16(a, b, c) __builtin_amdgcn_mfma_f32_16x16x16bf16_1k(a, b, c, 0, 0, 0)
#elif __has_builtin(__builtin_amdgcn_mfma_f32_16x16x16_bf16)
#define MFMA16(a, b, c) __builtin_amdgcn_mfma_f32_16x16x16_bf16(a, b, c, 0, 0, 0)
#else
#error "no 16x16x16 bf16 mfma builtin on device"
#endif
#if __has_builtin(__builtin_amdgcn_mfma_f32_16x16x16f16)
#define MFMA16H(a, b, c) __builtin_amdgcn_mfma_f32_16x16x16f16(a, b, c, 0, 0, 0)
#elif __has_builtin(__builtin_amdgcn_mfma_f32_16x16x16_f16)
#define MFMA16H(a, b, c) __builtin_amdgcn_mfma_f32_16x16x16_f16(a, b, c, 0, 0, 0)
#else
#error "no 16x16x16 f16 mfma builtin on device"
#endif
#if __has_builtin(__builtin_amdgcn_exp2f)
#define EXP2F(x) __builtin_amdgcn_exp2f(x)
#else
#define EXP2F(x) exp2f(x)
#endif
#else
#define MFMA16(a, b, c) (c)
#define MFMA16H(a, b, c) (c)
#define EXP2F(x) exp2f(x)
#endif

__device__ inline halfx2 cvt_pk2(float a, float b) {
#if defined(__HIP_DEVICE_COMPILE__) && __has_builtin(__builtin_amdgcn_cvt_pkrtz)
  auto r = __builtin_amdgcn_cvt_pkrtz(a, b);
  return __builtin_bit_cast(halfx2, r);
#else
  halfx2 r;
  r[0] = (_Float16)a;
  r[1] = (_Float16)b;
  return r;
#endif
}

__device__ inline unsigned short f2bf(float x) {
  __hip_bfloat16 h = __float2bfloat16(x);
  return *reinterpret_cast<unsigned short*>(&h);
}
__device__ inline float tanh_fast(float v) {
  return 1.f - 2.f / (__expf(2.f * v) + 1.f);
}

// ---------------- K1: fused prep über-kernel (4 independent segments) ----------------
// seg A [0,512):    A16 = bf16(rowsoftmax(relu(E E^T))), 4 rows/block
// seg B [512,768):  cT16[b][o][m] = bf16(c[b][m][o])
// seg C [768,800):  WpT[o][ktot] = fp16(Wp[ktot][o])
// seg D [800,1056): th16h/thq16h from state (fp16, Q pre-scaled)
__global__ __launch_bounds__(256) void k_preps(const float* __restrict__ E,
                                               const float* __restrict__ c,
                                               const float* __restrict__ state,
                                               const float* __restrict__ Wp,
                                               unsigned short* __restrict__ A16,
                                               unsigned short* __restrict__ cT16,
                                               half_t* __restrict__ WpT,
                                               half_t* __restrict__ th16h,
                                               half_t* __restrict__ thq16h) {
  __shared__ float sbuf[4 * 2304];  // 36,864 B union: rowsoftmax row[4][2048]+red[4][256] | ld[64][68]
  const int id = blockIdx.x;
  const int t = threadIdx.x;
  if (id < 512) {
    // ---- seg A: rowsoftmax, 4 rows ----
    float(*row)[NN] = (float(*)[NN])sbuf;
    float(*red)[256] = (float(*)[256])(sbuf + 4 * NN);
    const int n = id * 4;
    float4 e[4][4];
#pragma unroll
    for (int r = 0; r < 4; ++r) {
      const float4* Er = (const float4*)(E + (size_t)(n + r) * ADA);
#pragma unroll
      for (int j = 0; j < 4; ++j) e[r][j] = Er[j];
    }
    float l[4] = {0.f, 0.f, 0.f, 0.f};
    for (int m = t; m < NN; m += 256) {
      const float4* Em = (const float4*)(E + (size_t)m * ADA);
      float4 ev[4];
#pragma unroll
      for (int j = 0; j < 4; ++j) ev[j] = Em[j];
#pragma unroll
      for (int r = 0; r < 4; ++r) {
        float s = 0.f;
#pragma unroll
        for (int j = 0; j < 4; ++j) {
          s = fmaf(e[r][j].x, ev[j].x, s);
          s = fmaf(e[r][j].y, ev[j].y, s);
          s = fmaf(e[r][j].z, ev[j].z, s);
          s = fmaf(e[r][j].w, ev[j].w, s);
        }
        float p = __expf(fmaxf(s, 0.f) - 20.f);  // fixed shift; cancels in normalize
        row[r][m] = p;
        l[r] += p;
      }
    }
#pragma unroll
    for (int r = 0; r < 4; ++r) red[r][t] = l[r];
    __syncthreads();
    for (int off = 128; off > 0; off >>= 1) {
      if (t < off) {
#pragma unroll
        for (int r = 0; r < 4; ++r) red[r][t] += red[r][t + off];
      }
      __syncthreads();
    }
    float inv[4];
#pragma unroll
    for (int r = 0; r < 4; ++r) inv[r] = 1.f / red[r][0];
    for (int m = t; m < NN; m += 256) {
#pragma unroll
      for (int r = 0; r < 4; ++r)
        A16[(size_t)(n + r) * NN + m] = f2bf(row[r][m] * inv[r]);
    }
  } else if (id < 768) {
    // ---- seg B: c transpose -> bf16 ----
    float(*ld)[68] = (float(*)[68])sbuf;
    const int idx = id - 512;
    const int m0 = (idx & 31) * 64;
    const int b = idx >> 5;
    {
      const int r = t & 63, cq = t >> 6;
      const float* cp = c + ((size_t)b * NN + m0 + r) * LL + cq * 16;
#pragma unroll
      for (int u = 0; u < 4; ++u)
        *(float4*)&ld[r][cq * 16 + 4 * u] = *(const float4*)(cp + 4 * u);
    }
    __syncthreads();
    const int o = t & 63, mq = t >> 6;
    unsigned short outv[16];
#pragma unroll
    for (int v = 0; v < 16; ++v) outv[v] = f2bf(ld[mq * 16 + v][o]);
    unsigned short* op = cT16 + ((size_t)b * LL + o) * NN + m0 + mq * 16;
    *(ushort8v*)op = *(const ushort8v*)&outv[0];
    *(ushort8v*)(op + 8) = *(const ushort8v*)&outv[8];
  } else if (id < 800) {
    // ---- seg C: Wp transpose -> fp16 ----
    float(*ld)[68] = (float(*)[68])sbuf;
    const int k0 = (id - 768) * 64;
    {
      const int r = t & 63, cq = t >> 6;
      const float* wp = Wp + (size_t)(k0 + r) * LL + cq * 16;
#pragma unroll
      for (int u = 0; u < 4; ++u)
        *(float4*)&ld[r][cq * 16 + 4 * u] = *(const float4*)(wp + 4 * u);
    }
    __syncthreads();
    const int o = t & 63, kq = t >> 6;
    halfx8 h0, h1;
#pragma unroll
    for (int v = 0; v < 8; ++v) {
      h0[v] = (half_t)ld[kq * 16 + v][o];
      h1[v] = (half_t)ld[kq * 16 + 8 + v][o];
    }
    half_t* op = WpT + (size_t)o * KT + k0 + kq * 16;
    *(halfx8*)op = h0;
    *(halfx8*)(op + 8) = h1;
  } else {
    // ---- seg D: th/thq from state (thread: row r, head h) ----
    const int idx = id - 800;
    const int n0 = (idx & 31) * 64;
    const int b = idx >> 5;
    const int r = t >> 2, h = t & 3;
    const float QS = 0.25f * 1.4426950408889634f;  // score scale + log2(e) into Q
    const float* sp = state + ((size_t)b * NN + n0 + r) * LL + h * DH;
    half_t tk[16], tq[16];
#pragma unroll
    for (int u = 0; u < 4; ++u) {
      float4 sv = *(const float4*)(sp + 4 * u);
      tk[4 * u + 0] = (half_t)sv.x; tk[4 * u + 1] = (half_t)sv.y;
      tk[4 * u + 2] = (half_t)sv.z; tk[4 * u + 3] = (half_t)sv.w;
      tq[4 * u + 0] = (half_t)(QS * sv.x); tq[4 * u + 1] = (half_t)(QS * sv.y);
      tq[4 * u + 2] = (half_t)(QS * sv.z); tq[4 * u + 3] = (half_t)(QS * sv.w);
    }
    const size_t base = ((size_t)(h * 8 + b) * NN + n0 + r) * DH;
    *(halfx8*)(th16h + base) = *(const halfx8*)&tk[0];
    *(halfx8*)(th16h + base + 8) = *(const halfx8*)&tk[8];
    *(halfx8*)(thq16h + base) = *(const halfx8*)&tq[0];
    *(halfx8*)(thq16h + base + 8) = *(const halfx8*)&tq[8];
  }
}

// ---------------- K2: cg[b] = A @ c[b], bf16 16x16x16 MFMA (validated), K-split x2 ----------------
__global__ __launch_bounds__(256) void k_gemm1(const unsigned short* __restrict__ A16,
                                               const unsigned short* __restrict__ cT16,
                                               float* __restrict__ cg0,
                                               float* __restrict__ cg1) {
  __shared__ unsigned short sA[64][72];
  __shared__ unsigned short sB[64][72];
  const int t = threadIdx.x;
  const int n0 = blockIdx.x * 64;
  const int b = blockIdx.y;
  const int kh = blockIdx.z;
  const int wv = t >> 6, lane = t & 63;
  const int lr = lane & 15, lg = lane >> 4;
  const unsigned short* cb = cT16 + (size_t)b * LL * NN;
  const int sr = t >> 2, sc = (t & 3) * 16;
  f32x4 acc[4];
#pragma unroll
  for (int ot = 0; ot < 4; ++ot) acc[ot] = (f32x4){0.f, 0.f, 0.f, 0.f};

  for (int k0 = kh * (NN / 2); k0 < (kh + 1) * (NN / 2); k0 += 64) {
    __syncthreads();
    {
      const unsigned short* ga = A16 + (size_t)(n0 + sr) * NN + k0 + sc;
      *(ushort8v*)&sA[sr][sc] = *(const ushort8v*)ga;
      *(ushort8v*)&sA[sr][sc + 8] = *(const ushort8v*)(ga + 8);
      const unsigned short* gb = cb + (size_t)sr * NN + k0 + sc;
      *(ushort8v*)&sB[sr][sc] = *(const ushort8v*)gb;
      *(ushort8v*)&sB[sr][sc + 8] = *(const ushort8v*)(gb + 8);
    }
    __syncthreads();
#pragma unroll
    for (int ks = 0; ks < 4; ++ks) {
      bf16x4 a = *(const bf16x4*)&sA[16 * wv + lr][ks * 16 + 4 * lg];
#pragma unroll
      for (int ot = 0; ot < 4; ++ot) {
        bf16x4 bq = *(const bf16x4*)&sB[ot * 16 + lr][ks * 16 + 4 * lg];
        acc[ot] = MFMA16(a, bq, acc[ot]);
      }
    }
  }
  float* outp = (kh ? cg1 : cg0) + ((size_t)b * NN + n0 + 16 * wv) * LL;
#pragma unroll
  for (int ot = 0; ot < 4; ++ot)
#pragma unroll
    for (int reg = 0; reg < 4; ++reg)
      outp[(size_t)(4 * lg + reg) * LL + ot * 16 + lr] = acc[ot][reg];
}

// ---------------- K3: gcn4 — ct = tanh(sum_d E*(xg@Wp[d]) + E@bp), o-split x2, fused vt write ----------------
// Full d-loop per block (no dh split) => complete sum in-register => tanh + direct vt16h store.
__global__ __launch_bounds__(256) void k_gcn4(const float* __restrict__ E,
                                              const half_t* __restrict__ WpT,
                                              const float* __restrict__ bp,
                                              const float* __restrict__ c,
                                              const float* __restrict__ cg0,
                                              const float* __restrict__ cg1,
                                              half_t* __restrict__ vt16h) {
  __shared__ half_t sW[32][136];  // 32 o-rows x 128 k (per d) + pad, 8.7 KB
  __shared__ float sE[64][17];
  __shared__ float sbp[16][32];
  const int t = threadIdx.x;
  const int n0 = blockIdx.x * 64;
  const int b = blockIdx.y;
  const int oh = blockIdx.z;  // o in [oh*32, oh*32+32)
  const int wv = t >> 6, lane = t & 63;
  const int lr = lane & 15, lg = lane >> 4;
  {
    const int r = t >> 2, dq = (t & 3) * 4;
    float4 ev = *(const float4*)(E + (size_t)(n0 + r) * ADA + dq);
    sE[r][dq + 0] = ev.x; sE[r][dq + 1] = ev.y;
    sE[r][dq + 2] = ev.z; sE[r][dq + 3] = ev.w;
    const int d = t >> 4, o2 = (t & 15) * 2;  // bias slice [16][32]
    float2 bv = *(const float2*)(bp + d * LL + oh * 32 + o2);
    sbp[d][o2] = bv.x;
    sbp[d][o2 + 1] = bv.y;
  }
  // x (c | cg0+cg1) into registers. A-frag row = lr, k = 4*lg+j per 16-k tile.
  float xr[8][4];
  {
    const size_t rbase = ((size_t)b * NN + n0 + 16 * wv + lr) * LL;
#pragma unroll
    for (int q = 0; q < 4; ++q) {
      float4 v = *(const float4*)(c + rbase + q * 16 + 4 * lg);
      xr[q][0] = v.x; xr[q][1] = v.y; xr[q][2] = v.z; xr[q][3] = v.w;
    }
#pragma unroll
    for (int q = 0; q < 4; ++q) {
      float4 a = *(const float4*)(cg0 + rbase + q * 16 + 4 * lg);
      float4 b2 = *(const float4*)(cg1 + rbase + q * 16 + 4 * lg);
      xr[4 + q][0] = a.x + b2.x; xr[4 + q][1] = a.y + b2.y;
      xr[4 + q][2] = a.z + b2.z; xr[4 + q][3] = a.w + b2.w;
    }
  }
  __syncthreads();
  // acc init with bias; D rows = 16wv+4lg+reg (n), cols = ot2*16+lr (o local)
  f32x4 acc[2];
#pragma unroll
  for (int ot2 = 0; ot2 < 2; ++ot2) {
    f32x4 s = (f32x4){0.f, 0.f, 0.f, 0.f};
#pragma unroll
    for (int d = 0; d < ADA; ++d) {
      const float bpv = sbp[d][ot2 * 16 + lr];
#pragma unroll
      for (int reg = 0; reg < 4; ++reg)
        s[reg] = fmaf(sE[16 * wv + 4 * lg + reg][d], bpv, s[reg]);
    }
    acc[ot2] = s;
  }
  // W staging: thread covers o-row so (0..31), 16-half chunk sq (0..7)
  const int so = t >> 3, sq = t & 7;
  halfx8 wreg[2];
  {
    const half_t* p = WpT + (size_t)(oh * 32 + so) * KT + sq * 16;
    wreg[0] = *(const halfx8*)p;
    wreg[1] = *(const halfx8*)(p + 8);
  }
  for (int dd = 0; dd < ADA; ++dd) {
    __syncthreads();  // previous iteration's MFMAs done with sW
    *(halfx8*)&sW[so][sq * 16] = wreg[0];
    *(halfx8*)&sW[so][sq * 16 + 8] = wreg[1];
    __syncthreads();  // sW ready
    if (dd < ADA - 1) {
      const half_t* p = WpT + (size_t)(oh * 32 + so) * KT + (dd + 1) * 128 + sq * 16;
      wreg[0] = *(const halfx8*)p;
      wreg[1] = *(const halfx8*)(p + 8);
    }
    const float e = sE[16 * wv + lr][dd];
    halfx4 af[8];
#pragma unroll
    for (int kt = 0; kt < 8; ++kt)
#pragma unroll
      for (int j = 0; j < 4; ++j) af[kt][j] = (half_t)(e * xr[kt][j]);
#pragma unroll
    for (int kt = 0; kt < 8; ++kt) {
#pragma unroll
      for (int ot2 = 0; ot2 < 2; ++ot2) {
        halfx4 bq = *(const halfx4*)&sW[ot2 * 16 + lr][kt * 16 + 4 * lg];
        acc[ot2] = MFMA16H(af[kt], bq, acc[ot2]);
      }
    }
  }
  // epilogue: tanh + direct transposed fp16 store to vt16h[hb][d=lr][n]
#pragma unroll
  for (int ot2 = 0; ot2 < 2; ++ot2) {
    const int h = oh * 2 + ot2;
    halfx4 o4;
#pragma unroll
    for (int reg = 0; reg < 4; ++reg) o4[reg] = (half_t)tanh_fast(acc[ot2][reg]);
    *(halfx4*)(vt16h + ((size_t)(h * 8 + b) * DH + lr) * NN + n0 + 16 * wv + 4 * lg) = o4;
  }
}

// ---------------- K4: fp16 MFMA attention — 128 q/block (8 frags/wave), m split 8-way ----------------
__global__ __launch_bounds__(512, 4) void k_attn5(const half_t* __restrict__ th16h,
                                                  const half_t* __restrict__ thq16h,
                                                  const half_t* __restrict__ vt16h,
                                                  float* __restrict__ out) {
  __shared__ float sred[8][8][16][16];  // 64 KB: phase A den (first 4 KB), phase B num
  float* dfl = &sred[0][0][0][0];
  const int hb = blockIdx.x;
  const int h = hb >> 3, b = hb & 7;
  const int wv = threadIdx.x >> 6, lane = threadIdx.x & 63;
  const int q0 = blockIdx.y * 128;
  const int lr = lane & 15, lg = lane >> 4;
  const half_t* th = th16h + (size_t)hb * NN * DH;
  const half_t* thq = thq16h + (size_t)hb * NN * DH;
  const half_t* vrow = vt16h + ((size_t)hb * DH + lr) * NN;  // V^T row d=lr
  halfx4 qf[8];
#pragma unroll
  for (int f = 0; f < 8; ++f)
    qf[f] = *(const halfx4*)(thq + (size_t)(q0 + 16 * f + lr) * DH + 4 * lg);
  // shift-8 softmax via MFMA C-init (fp16-safe, cancels in num/den)
  const float SH = 8.f * 1.4426950408889634f;
  const f32x4 shiftv = {-SH, -SH, -SH, -SH};
  f32x4 acc[8];
  float den[8];
#pragma unroll
  for (int f = 0; f < 8; ++f) { acc[f] = (f32x4){0.f, 0.f, 0.f, 0.f}; den[f] = 0.f; }

  const int mb = wv * (NN / 8);  // this wave's 256-row m-slice
  halfx4 kf = *(const halfx4*)(th + (size_t)(mb + lr) * DH + 4 * lg);
  halfx4 vf = *(const halfx4*)(vrow + mb + 4 * lg);
  for (int mt = 0; mt < NN / 128; ++mt) {  // 16 tiles of 16
    halfx4 kf_n = kf, vf_n = vf;
    if (mt < NN / 128 - 1) {
      const int mn = mb + (mt + 1) * 16;
      kf_n = *(const halfx4*)(th + (size_t)(mn + lr) * DH + 4 * lg);
      vf_n = *(const halfx4*)(vrow + mn + 4 * lg);
    }
#pragma unroll
    for (int f = 0; f < 8; ++f) {
      f32x4 s = MFMA16H(kf, qf[f], shiftv);  // lane: col q, rows m; pre-shifted
      float p0 = EXP2F(s[0]), p1 = EXP2F(s[1]), p2 = EXP2F(s[2]), p3 = EXP2F(s[3]);
      den[f] += (p0 + p1) + (p2 + p3);
      halfx2 lo = cvt_pk2(p0, p1), hi = cvt_pk2(p2, p3);
      halfx4 pf;
      pf[0] = lo[0]; pf[1] = lo[1]; pf[2] = hi[0]; pf[3] = hi[1];
      acc[f] = MFMA16H(pf, vf, acc[f]);  // lane: col d=lr, rows q=16f+4lg+reg
    }
    kf = kf_n; vf = vf_n;
  }
#pragma unroll
  for (int f = 0; f < 8; ++f) {
    den[f] += __shfl_xor(den[f], 16);
    den[f] += __shfl_xor(den[f], 32);
  }
  // phase A: den partials (8 waves x 8 frags x 16 q = 4 KB of sred)
  if (lane < 16) {
#pragma unroll
    for (int f = 0; f < 8; ++f) dfl[(wv * 8 + f) * 16 + lane] = den[f];
  }
  __syncthreads();
  const int t = threadIdx.x;
  const int fo = t >> 6, ro = (t >> 2) & 15, duo = (t & 3) * 4;
  float ds = 0.f;
#pragma unroll
  for (int w = 0; w < 8; ++w) ds += dfl[(w * 8 + fo) * 16 + ro];
  __syncthreads();  // done reading den region before overwrite
  // phase B: numerator partials
#pragma unroll
  for (int f = 0; f < 8; ++f) {
#pragma unroll
    for (int reg = 0; reg < 4; ++reg) sred[wv][f][4 * lg + reg][lr] = acc[f][reg];
  }
  __syncthreads();
  float4 ns = make_float4(0.f, 0.f, 0.f, 0.f);
#pragma unroll
  for (int w = 0; w < 8; ++w) {
    float4 v = *(const float4*)&sred[w][fo][ro][duo];
    ns.x += v.x; ns.y += v.y; ns.z += v.z; ns.w += v.w;
  }
  const float inv = -1.f / ds;
  float4 o = make_float4(ns.x * inv, ns.y * inv, ns.z * inv, ns.w * inv);
  *(float4*)(out + ((size_t)b * NN + q0 + 16 * fo + ro) * LL + h * DH + duo) = o;
}

extern "C" void kernel_launch(void* const* d_in, const int* in_sizes, int n_in,
                              void* d_out, int out_size, void* d_ws, size_t ws_size,
                              hipStream_t stream) {
  const float* c = (const float*)d_in[0];
  const float* state = (const float*)d_in[3];
  const float* E = (const float*)d_in[4];
  const float* Wp = (const float*)d_in[13];
  const float* bp = (const float*)d_in[14];
  float* out = (float*)d_out;

  unsigned short* A16 = (unsigned short*)d_ws;        // 2048*2048 bf16 = 8 MB
  unsigned short* cT16 = A16 + (size_t)NN * NN;       // 2 MB
  half_t* WpT = (half_t*)(cT16 + (size_t)BB * LL * NN);  // 256 KB
  float* cg0 = (float*)(WpT + (size_t)LL * KT);       // 4 MB
  float* cg1 = cg0 + (size_t)BB * NN * LL;            // 4 MB
  half_t* th16h = (half_t*)(cg1 + (size_t)BB * NN * LL);  // 2 MB
  half_t* thq16h = th16h + (size_t)HB * NN * DH;          // 2 MB
  half_t* vt16h = thq16h + (size_t)HB * NN * DH;          // 2 MB

  k_preps<<<1056, 256, 0, stream>>>(E, c, state, Wp, A16, cT16, WpT, th16h, thq16h);
  k_gemm1<<<dim3(NN / 64, BB, 2), 256, 0, stream>>>(A16, cT16, cg0, cg1);
  k_gcn4<<<dim3(NN / 64, BB, 2), 256, 0, stream>>>(E, WpT, bp, c, cg0, cg1, vt16h);
  k_attn5<<<dim3(HB, NN / 128), 512, 0, stream>>>(th16h, thq16h, vt16h, out);
}